// Round 1
// baseline (312.091 us; speedup 1.0000x reference)
//
#include <hip/hip_runtime.h>
#include <stdint.h>

typedef __attribute__((ext_vector_type(8))) short bf16x8;
typedef __attribute__((ext_vector_type(4))) float f32x4;
typedef __attribute__((ext_vector_type(8))) unsigned short ushort8;
typedef __attribute__((ext_vector_type(4))) unsigned short ushort4v;

#define MFMA16(a, b, c) __builtin_amdgcn_mfma_f32_16x16x32_bf16((a), (b), (c), 0, 0, 0)

// B=8, S=1024, D=1024, H=16, DK=64
#define SLEN 1024
#define NHEAD 16
#define HDIM 64
#define DMODEL 1024
#define NROWS 8192  // B*S

__device__ __forceinline__ unsigned short f2bf(float f) {
  unsigned int u = __float_as_uint(f);
  u += 0x7FFFu + ((u >> 16) & 1u);   // RNE
  return (unsigned short)(u >> 16);
}

// ---------------- convert hidden_states f32 -> bf16 ----------------
__global__ __launch_bounds__(256) void k_convert_x(const float* __restrict__ x,
                                                   unsigned short* __restrict__ xb, int n) {
  int i = blockIdx.x * 256 + threadIdx.x;
  int idx = i * 8;
  if (idx >= n) return;
  float4 a = *(const float4*)(x + idx);
  float4 b = *(const float4*)(x + idx + 4);
  ushort8 o;
  o[0] = f2bf(a.x); o[1] = f2bf(a.y); o[2] = f2bf(a.z); o[3] = f2bf(a.w);
  o[4] = f2bf(b.x); o[5] = f2bf(b.y); o[6] = f2bf(b.z); o[7] = f2bf(b.w);
  *(ushort8*)(xb + idx) = o;
}

// ---------------- transpose + convert weights: W[K][N] f32 -> Wt[N][K] bf16 ----------------
__global__ __launch_bounds__(256) void k_transpose_w(
    const float* __restrict__ w0, const float* __restrict__ w1,
    const float* __restrict__ w2, const float* __restrict__ w3,
    unsigned short* __restrict__ o0, unsigned short* __restrict__ o1,
    unsigned short* __restrict__ o2, unsigned short* __restrict__ o3) {
  int z = blockIdx.z;
  const float* w = (z == 0) ? w0 : (z == 1) ? w1 : (z == 2) ? w2 : w3;
  unsigned short* o = (z == 0) ? o0 : (z == 1) ? o1 : (z == 2) ? o2 : o3;
  __shared__ unsigned short tile[32][33];
  int bx = blockIdx.x & 31, by = blockIdx.x >> 5;   // bx: col tile, by: row tile
  int tid = threadIdx.x;
#pragma unroll
  for (int p = 0; p < 4; ++p) {
    int idx = tid + p * 256;
    int r = idx >> 5, c = idx & 31;
    tile[r][c] = f2bf(w[(size_t)(by * 32 + r) * DMODEL + bx * 32 + c]);
  }
  __syncthreads();
#pragma unroll
  for (int p = 0; p < 4; ++p) {
    int idx = tid + p * 256;
    int r = idx >> 5, c = idx & 31;
    o[(size_t)(bx * 32 + r) * DMODEL + by * 32 + c] = tile[c][r];
  }
}

// ---------------- relative-position bias table: bt[h][rel+1023], rel=k-q ----------------
__global__ __launch_bounds__(256) void k_bias_table(const float* __restrict__ rel_bias,
                                                    float* __restrict__ bt) {
  int i = blockIdx.x * 256 + threadIdx.x;
  if (i >= NHEAD * 2047) return;
  int h = i / 2047, rdx = i % 2047;
  int rel = rdx - 1023;
  int rb = (rel > 0) ? 16 : 0;
  int rp = (rel < 0) ? -rel : rel;
  int bucket;
  if (rp < 8) {
    bucket = rb + rp;
  } else {
    // large = 8 + floor(log(rp/8)/log(16)*8) = 8 + floor(2*log2(rp)) - 6, capped at 15.
    // Integer-exact: floor(2*log2 rp) = 2*nb + [rp^2 >= 2^(2nb+1)]
    int large;
    if (rp >= 91) {
      large = 15;
    } else {
      int nb = 31 - __clz(rp);
      long long sq = (long long)rp * rp;
      int f2 = 2 * nb + ((sq >= (1LL << (2 * nb + 1))) ? 1 : 0);
      large = 8 + (f2 - 6);
      if (large > 15) large = 15;
    }
    bucket = rb + large;
  }
  bt[h * 2048 + rdx] = rel_bias[bucket * 16 + h];
}

// ---------------- shared GEMM core: C[128x128] = A[M][K] * Bt[N][K]^T ----------------
// 256 threads = 4 waves (2x2), per-wave 64x64, mfma_f32_16x16x32_bf16, BK=32.
// LDS padded stride 40 shorts (2-way bank conflict only).
__device__ __forceinline__ void gemm_tile_core(const unsigned short* __restrict__ A,
                                               const unsigned short* __restrict__ Bt,
                                               int K, int tm, int tn,
                                               unsigned short* As, unsigned short* Bs,
                                               f32x4 acc[4][4]) {
  const int tid = threadIdx.x;
  const int lane = tid & 63;
  const int w = tid >> 6;
  const int wr = w >> 1, wc = w & 1;
  const int g = lane >> 4, t = lane & 15;
  const int NKT = K >> 5;

  // staging: 2 chunks per thread for each of A and B; chunk c -> row c>>2, kcol (c&3)*8
  const int r0 = tid >> 2, kc = (tid & 3) * 8;
  const int r1 = r0 + 64;
  const unsigned short* Ag0 = A + (size_t)(tm + r0) * K + kc;
  const unsigned short* Ag1 = A + (size_t)(tm + r1) * K + kc;
  const unsigned short* Bg0 = Bt + (size_t)(tn + r0) * K + kc;
  const unsigned short* Bg1 = Bt + (size_t)(tn + r1) * K + kc;

  f32x4 z = {0.f, 0.f, 0.f, 0.f};
#pragma unroll
  for (int mi = 0; mi < 4; ++mi)
#pragma unroll
    for (int ni = 0; ni < 4; ++ni) acc[mi][ni] = z;

  bf16x8 ra0 = *(const bf16x8*)(Ag0);
  bf16x8 ra1 = *(const bf16x8*)(Ag1);
  bf16x8 rb0 = *(const bf16x8*)(Bg0);
  bf16x8 rb1 = *(const bf16x8*)(Bg1);

  for (int kt = 0; kt < NKT; ++kt) {
    __syncthreads();
    *(bf16x8*)&As[r0 * 40 + kc] = ra0;
    *(bf16x8*)&As[r1 * 40 + kc] = ra1;
    *(bf16x8*)&Bs[r0 * 40 + kc] = rb0;
    *(bf16x8*)&Bs[r1 * 40 + kc] = rb1;
    __syncthreads();
    if (kt + 1 < NKT) {
      int off = (kt + 1) * 32;
      ra0 = *(const bf16x8*)(Ag0 + off);
      ra1 = *(const bf16x8*)(Ag1 + off);
      rb0 = *(const bf16x8*)(Bg0 + off);
      rb1 = *(const bf16x8*)(Bg1 + off);
    }
    bf16x8 af[4], bfr[4];
#pragma unroll
    for (int mi = 0; mi < 4; ++mi)
      af[mi] = *(const bf16x8*)&As[(wr * 64 + mi * 16 + t) * 40 + g * 8];
#pragma unroll
    for (int ni = 0; ni < 4; ++ni)
      bfr[ni] = *(const bf16x8*)&Bs[(wc * 64 + ni * 16 + t) * 40 + g * 8];
#pragma unroll
    for (int mi = 0; mi < 4; ++mi)
#pragma unroll
      for (int ni = 0; ni < 4; ++ni)
        acc[mi][ni] = MFMA16(af[mi], bfr[ni], acc[mi][ni]);
  }
}

// ---------------- QKV projection: z=0 Q, z=1 K (layout [BH][S][64]), z=2 V transposed [BH][64][S] ----------------
__global__ __launch_bounds__(256) void k_gemm_qkv(
    const unsigned short* __restrict__ Xb,
    const unsigned short* __restrict__ Wqt, const unsigned short* __restrict__ Wkt,
    const unsigned short* __restrict__ Wvt,
    unsigned short* __restrict__ Qb, unsigned short* __restrict__ Kb,
    unsigned short* __restrict__ Vt) {
  __shared__ alignas(16) unsigned short As[128 * 40];
  __shared__ alignas(16) unsigned short Bs[128 * 40];
  int z = blockIdx.z;
  const unsigned short* Bt = (z == 0) ? Wqt : (z == 1) ? Wkt : Wvt;
  int tm = (blockIdx.x >> 3) * 128, tn = (blockIdx.x & 7) * 128;
  f32x4 acc[4][4];
  gemm_tile_core(Xb, Bt, DMODEL, tm, tn, As, Bs, acc);

  const int lane = threadIdx.x & 63, w = threadIdx.x >> 6;
  const int wr = w >> 1, wc = w & 1, g = lane >> 4, t = lane & 15;
  if (z < 2) {
    unsigned short* O = (z == 0) ? Qb : Kb;
#pragma unroll
    for (int mi = 0; mi < 4; ++mi)
#pragma unroll
      for (int ni = 0; ni < 4; ++ni)
#pragma unroll
        for (int r = 0; r < 4; ++r) {
          int m = tm + wr * 64 + mi * 16 + g * 4 + r;
          int n = tn + wc * 64 + ni * 16 + t;
          int b = m >> 10, s = m & 1023, h = n >> 6, d = n & 63;
          O[((size_t)((b * 16 + h) * 1024 + s)) * 64 + d] = f2bf(acc[mi][ni][r]);
        }
  } else {
#pragma unroll
    for (int mi = 0; mi < 4; ++mi)
#pragma unroll
      for (int ni = 0; ni < 4; ++ni) {
        int m0 = tm + wr * 64 + mi * 16 + g * 4;
        int n = tn + wc * 64 + ni * 16 + t;
        int b = m0 >> 10, s0 = m0 & 1023, h = n >> 6, d = n & 63;
        ushort4v pk;
#pragma unroll
        for (int r = 0; r < 4; ++r) pk[r] = f2bf(acc[mi][ni][r]);
        *(ushort4v*)&Vt[((size_t)((b * 16 + h) * 64 + d) * 1024) + s0] = pk;
      }
  }
}

// ---------------- flash attention ----------------
// grid: BH*8 blocks; block 256 = 4 waves; wave handles 32 q-rows; k-tiles of 64.
__global__ __launch_bounds__(256) void k_attn(
    const unsigned short* __restrict__ Qb, const unsigned short* __restrict__ Kb,
    const unsigned short* __restrict__ Vt, const float* __restrict__ bt,
    unsigned short* __restrict__ ctx) {
  __shared__ alignas(16) unsigned short P_lds[4][32][72];  // per-wave, padded
  int bh = blockIdx.x >> 3, qb = blockIdx.x & 7;
  int h = bh & 15, b = bh >> 4;
  int lane = threadIdx.x & 63, w = threadIdx.x >> 6;
  int g = lane >> 4, t = lane & 15;
  int q0 = qb * 128 + w * 32;

  const unsigned short* Qp = Qb + (size_t)bh * SLEN * 64;
  const unsigned short* Kp = Kb + (size_t)bh * SLEN * 64;
  const unsigned short* Vp = Vt + (size_t)bh * 64 * SLEN;
  const float* hb = bt + h * 2048;

  // Q fragments (A layout): row=lane&15, k contiguous 8
  bf16x8 aq[2][2];
#pragma unroll
  for (int mi = 0; mi < 2; ++mi)
#pragma unroll
    for (int kk = 0; kk < 2; ++kk)
      aq[mi][kk] = *(const bf16x8*)(Qp + (size_t)(q0 + mi * 16 + t) * 64 + kk * 32 + g * 8);

  f32x4 o[2][4];
  float mrow[2][4], lrow[2][4];
  f32x4 z = {0.f, 0.f, 0.f, 0.f};
#pragma unroll
  for (int mi = 0; mi < 2; ++mi) {
#pragma unroll
    for (int dj = 0; dj < 4; ++dj) o[mi][dj] = z;
#pragma unroll
    for (int r = 0; r < 4; ++r) { mrow[mi][r] = -INFINITY; lrow[mi][r] = 0.f; }
  }

  for (int kt = 0; kt < 16; ++kt) {
    int kbase = kt * 64;
    // K fragments (B layout): col=lane&15 is the key index
    bf16x8 bk[4][2];
#pragma unroll
    for (int nj = 0; nj < 4; ++nj)
#pragma unroll
      for (int kk = 0; kk < 2; ++kk)
        bk[nj][kk] = *(const bf16x8*)(Kp + (size_t)(kbase + nj * 16 + t) * 64 + kk * 32 + g * 8);

    f32x4 s[2][4];
#pragma unroll
    for (int mi = 0; mi < 2; ++mi)
#pragma unroll
      for (int nj = 0; nj < 4; ++nj) {
        f32x4 a0 = MFMA16(aq[mi][0], bk[nj][0], z);
        s[mi][nj] = MFMA16(aq[mi][1], bk[nj][1], a0);
      }

    // bias add: S[q][k] += bt[h][k-q+1023]
#pragma unroll
    for (int mi = 0; mi < 2; ++mi)
#pragma unroll
      for (int nj = 0; nj < 4; ++nj)
#pragma unroll
        for (int r = 0; r < 4; ++r) {
          int qq = q0 + mi * 16 + g * 4 + r;
          int kc = kbase + nj * 16 + t;
          s[mi][nj][r] += hb[kc - qq + 1023];
        }

    // online softmax (row stats per (mi,r); 16-lane group reduce)
#pragma unroll
    for (int mi = 0; mi < 2; ++mi)
#pragma unroll
      for (int r = 0; r < 4; ++r) {
        float vm = s[mi][0][r];
#pragma unroll
        for (int nj = 1; nj < 4; ++nj) vm = fmaxf(vm, s[mi][nj][r]);
        vm = fmaxf(vm, __shfl_xor(vm, 1));
        vm = fmaxf(vm, __shfl_xor(vm, 2));
        vm = fmaxf(vm, __shfl_xor(vm, 4));
        vm = fmaxf(vm, __shfl_xor(vm, 8));
        float mn = fmaxf(mrow[mi][r], vm);
        float sc = __expf(mrow[mi][r] - mn);
        float ls = 0.f;
#pragma unroll
        for (int nj = 0; nj < 4; ++nj) {
          float pv = __expf(s[mi][nj][r] - mn);
          s[mi][nj][r] = pv;
          ls += pv;
        }
        lrow[mi][r] = lrow[mi][r] * sc + ls;
        mrow[mi][r] = mn;
#pragma unroll
        for (int dj = 0; dj < 4; ++dj) o[mi][dj][r] *= sc;
      }

    // P (C-layout) -> LDS -> A-layout fragments
#pragma unroll
    for (int mi = 0; mi < 2; ++mi)
#pragma unroll
      for (int nj = 0; nj < 4; ++nj)
#pragma unroll
        for (int r = 0; r < 4; ++r)
          P_lds[w][mi * 16 + g * 4 + r][nj * 16 + t] = f2bf(s[mi][nj][r]);

    bf16x8 pa[2][2];
#pragma unroll
    for (int mi = 0; mi < 2; ++mi)
#pragma unroll
      for (int kk = 0; kk < 2; ++kk)
        pa[mi][kk] = *(const bf16x8*)&P_lds[w][mi * 16 + t][kk * 32 + g * 8];

    // V fragments (B layout) from transposed V
    bf16x8 bv[4][2];
#pragma unroll
    for (int dj = 0; dj < 4; ++dj)
#pragma unroll
      for (int kk = 0; kk < 2; ++kk)
        bv[dj][kk] = *(const bf16x8*)(Vp + (size_t)(dj * 16 + t) * SLEN + kbase + kk * 32 + g * 8);

#pragma unroll
    for (int mi = 0; mi < 2; ++mi)
#pragma unroll
      for (int dj = 0; dj < 4; ++dj) {
        o[mi][dj] = MFMA16(pa[mi][0], bv[dj][0], o[mi][dj]);
        o[mi][dj] = MFMA16(pa[mi][1], bv[dj][1], o[mi][dj]);
      }
  }

  // finalize: reduce l across 16-lane group, divide, write ctx[b][q][h*64+d]
  float inv[2][4];
#pragma unroll
  for (int mi = 0; mi < 2; ++mi)
#pragma unroll
    for (int r = 0; r < 4; ++r) {
      float lv = lrow[mi][r];
      lv += __shfl_xor(lv, 1);
      lv += __shfl_xor(lv, 2);
      lv += __shfl_xor(lv, 4);
      lv += __shfl_xor(lv, 8);
      inv[mi][r] = 1.0f / lv;
    }
#pragma unroll
  for (int mi = 0; mi < 2; ++mi)
#pragma unroll
    for (int dj = 0; dj < 4; ++dj)
#pragma unroll
      for (int r = 0; r < 4; ++r) {
        int qq = q0 + mi * 16 + g * 4 + r;
        int d = dj * 16 + t;
        ctx[((size_t)(b * 1024 + qq)) * 1024 + h * 64 + d] = f2bf(o[mi][dj][r] * inv[mi][r]);
      }
}

// ---------------- output projection: out = ctx @ wo (f32 out) ----------------
__global__ __launch_bounds__(256) void k_gemm_out(
    const unsigned short* __restrict__ Cb, const unsigned short* __restrict__ Wot,
    float* __restrict__ out) {
  __shared__ alignas(16) unsigned short As[128 * 40];
  __shared__ alignas(16) unsigned short Bs[128 * 40];
  int tm = (blockIdx.x >> 3) * 128, tn = (blockIdx.x & 7) * 128;
  f32x4 acc[4][4];
  gemm_tile_core(Cb, Wot, DMODEL, tm, tn, As, Bs, acc);

  const int lane = threadIdx.x & 63, w = threadIdx.x >> 6;
  const int wr = w >> 1, wc = w & 1, g = lane >> 4, t = lane & 15;
#pragma unroll
  for (int mi = 0; mi < 4; ++mi)
#pragma unroll
    for (int ni = 0; ni < 4; ++ni)
#pragma unroll
      for (int r = 0; r < 4; ++r) {
        int m = tm + wr * 64 + mi * 16 + g * 4 + r;
        int n = tn + wc * 64 + ni * 16 + t;
        out[(size_t)m * DMODEL + n] = acc[mi][ni][r];
      }
}

extern "C" void kernel_launch(void* const* d_in, const int* in_sizes, int n_in,
                              void* d_out, int out_size, void* d_ws, size_t ws_size,
                              hipStream_t stream) {
  const float* hs = (const float*)d_in[0];
  const float* wq = (const float*)d_in[1];
  const float* wk = (const float*)d_in[2];
  const float* wv = (const float*)d_in[3];
  const float* wo = (const float*)d_in[4];
  const float* rb = (const float*)d_in[5];

  char* ws = (char*)d_ws;
  unsigned short* Xb  = (unsigned short*)(ws + 0);          // 16 MB
  unsigned short* Wqt = (unsigned short*)(ws + 16777216);   // 2 MB
  unsigned short* Wkt = (unsigned short*)(ws + 18874368);
  unsigned short* Wvt = (unsigned short*)(ws + 20971520);
  unsigned short* Wot = (unsigned short*)(ws + 23068672);
  unsigned short* Qb  = (unsigned short*)(ws + 25165824);   // 16 MB
  unsigned short* Kb  = (unsigned short*)(ws + 41943040);   // 16 MB
  unsigned short* Vt  = (unsigned short*)(ws + 58720256);   // 16 MB
  unsigned short* Cb  = (unsigned short*)(ws + 75497472);   // 16 MB
  float* bt           = (float*)(ws + 92274688);            // 128 KB

  k_convert_x<<<4096, 256, 0, stream>>>(hs, Xb, NROWS * DMODEL);
  k_transpose_w<<<dim3(1024, 1, 4), 256, 0, stream>>>(wq, wk, wv, wo, Wqt, Wkt, Wvt, Wot);
  k_bias_table<<<128, 256, 0, stream>>>(rb, bt);
  k_gemm_qkv<<<dim3(512, 1, 3), 256, 0, stream>>>(Xb, Wqt, Wkt, Wvt, Qb, Kb, Vt);
  k_attn<<<1024, 256, 0, stream>>>(Qb, Kb, Vt, bt, Cb);
  k_gemm_out<<<512, 256, 0, stream>>>(Cb, Wot, (float*)d_out);
}

// Round 2
// 266.506 us; speedup vs baseline: 1.1710x; 1.1710x over previous
//
#include <hip/hip_runtime.h>
#include <stdint.h>

typedef __attribute__((ext_vector_type(8))) short bf16x8;
typedef __attribute__((ext_vector_type(4))) float f32x4;
typedef __attribute__((ext_vector_type(8))) unsigned short ushort8;
typedef __attribute__((ext_vector_type(4))) unsigned short ushort4v;

#define MFMA16(a, b, c) __builtin_amdgcn_mfma_f32_16x16x32_bf16((a), (b), (c), 0, 0, 0)

// B=8, S=1024, D=1024, H=16, DK=64
#define SLEN 1024
#define NHEAD 16
#define HDIM 64
#define DMODEL 1024
#define NROWS 8192  // B*S
#define LOG2E 1.44269504088896340736f

__device__ __forceinline__ unsigned short f2bf(float f) {
  unsigned int u = __float_as_uint(f);
  u += 0x7FFFu + ((u >> 16) & 1u);   // RNE
  return (unsigned short)(u >> 16);
}

__device__ __forceinline__ float fast_exp2(float x) {
#if __has_builtin(__builtin_amdgcn_exp2f)
  return __builtin_amdgcn_exp2f(x);
#else
  float r; asm("v_exp_f32 %0, %1" : "=v"(r) : "v"(x)); return r;
#endif
}

// ---------------- convert hidden_states f32 -> bf16 ----------------
__global__ __launch_bounds__(256) void k_convert_x(const float* __restrict__ x,
                                                   unsigned short* __restrict__ xb, int n) {
  int i = blockIdx.x * 256 + threadIdx.x;
  int idx = i * 8;
  if (idx >= n) return;
  float4 a = *(const float4*)(x + idx);
  float4 b = *(const float4*)(x + idx + 4);
  ushort8 o;
  o[0] = f2bf(a.x); o[1] = f2bf(a.y); o[2] = f2bf(a.z); o[3] = f2bf(a.w);
  o[4] = f2bf(b.x); o[5] = f2bf(b.y); o[6] = f2bf(b.z); o[7] = f2bf(b.w);
  *(ushort8*)(xb + idx) = o;
}

// ---------------- transpose + convert weights: W[K][N] f32 -> Wt[N][K] bf16 ----------------
__global__ __launch_bounds__(256) void k_transpose_w(
    const float* __restrict__ w0, const float* __restrict__ w1,
    const float* __restrict__ w2, const float* __restrict__ w3,
    unsigned short* __restrict__ o0, unsigned short* __restrict__ o1,
    unsigned short* __restrict__ o2, unsigned short* __restrict__ o3) {
  int z = blockIdx.z;
  const float* w = (z == 0) ? w0 : (z == 1) ? w1 : (z == 2) ? w2 : w3;
  unsigned short* o = (z == 0) ? o0 : (z == 1) ? o1 : (z == 2) ? o2 : o3;
  __shared__ unsigned short tile[32][33];
  int bx = blockIdx.x & 31, by = blockIdx.x >> 5;
  int tid = threadIdx.x;
#pragma unroll
  for (int p = 0; p < 4; ++p) {
    int idx = tid + p * 256;
    int r = idx >> 5, c = idx & 31;
    tile[r][c] = f2bf(w[(size_t)(by * 32 + r) * DMODEL + bx * 32 + c]);
  }
  __syncthreads();
#pragma unroll
  for (int p = 0; p < 4; ++p) {
    int idx = tid + p * 256;
    int r = idx >> 5, c = idx & 31;
    o[(size_t)(bx * 32 + r) * DMODEL + by * 32 + c] = tile[c][r];
  }
}

// ---------------- relative-position bias table: bt[h][rel+1023] * log2e, rel=k-q ----------------
__global__ __launch_bounds__(256) void k_bias_table(const float* __restrict__ rel_bias,
                                                    float* __restrict__ bt) {
  int i = blockIdx.x * 256 + threadIdx.x;
  if (i >= NHEAD * 2047) return;
  int h = i / 2047, rdx = i % 2047;
  int rel = rdx - 1023;
  int rb = (rel > 0) ? 16 : 0;
  int rp = (rel < 0) ? -rel : rel;
  int bucket;
  if (rp < 8) {
    bucket = rb + rp;
  } else {
    // large = 8 + floor(2*log2(rp)) - 6, capped at 15. Integer-exact via clz+square.
    int large;
    if (rp >= 91) {
      large = 15;
    } else {
      int nb = 31 - __clz(rp);
      long long sq = (long long)rp * rp;
      int f2 = 2 * nb + ((sq >= (1LL << (2 * nb + 1))) ? 1 : 0);
      large = 8 + (f2 - 6);
      if (large > 15) large = 15;
    }
    bucket = rb + large;
  }
  bt[h * 2048 + rdx] = rel_bias[bucket * 16 + h] * LOG2E;  // log2e domain
}

// ---------------- shared GEMM core: C[128x128] = A[M][K] * Bt[N][K]^T ----------------
__device__ __forceinline__ void gemm_tile_core(const unsigned short* __restrict__ A,
                                               const unsigned short* __restrict__ Bt,
                                               int K, int tm, int tn,
                                               unsigned short* As, unsigned short* Bs,
                                               f32x4 acc[4][4]) {
  const int tid = threadIdx.x;
  const int lane = tid & 63;
  const int w = tid >> 6;
  const int wr = w >> 1, wc = w & 1;
  const int g = lane >> 4, t = lane & 15;
  const int NKT = K >> 5;

  const int r0 = tid >> 2, kc = (tid & 3) * 8;
  const int r1 = r0 + 64;
  const unsigned short* Ag0 = A + (size_t)(tm + r0) * K + kc;
  const unsigned short* Ag1 = A + (size_t)(tm + r1) * K + kc;
  const unsigned short* Bg0 = Bt + (size_t)(tn + r0) * K + kc;
  const unsigned short* Bg1 = Bt + (size_t)(tn + r1) * K + kc;

  f32x4 z = {0.f, 0.f, 0.f, 0.f};
#pragma unroll
  for (int mi = 0; mi < 4; ++mi)
#pragma unroll
    for (int ni = 0; ni < 4; ++ni) acc[mi][ni] = z;

  bf16x8 ra0 = *(const bf16x8*)(Ag0);
  bf16x8 ra1 = *(const bf16x8*)(Ag1);
  bf16x8 rb0 = *(const bf16x8*)(Bg0);
  bf16x8 rb1 = *(const bf16x8*)(Bg1);

  for (int kt = 0; kt < NKT; ++kt) {
    __syncthreads();
    *(bf16x8*)&As[r0 * 40 + kc] = ra0;
    *(bf16x8*)&As[r1 * 40 + kc] = ra1;
    *(bf16x8*)&Bs[r0 * 40 + kc] = rb0;
    *(bf16x8*)&Bs[r1 * 40 + kc] = rb1;
    __syncthreads();
    if (kt + 1 < NKT) {
      int off = (kt + 1) * 32;
      ra0 = *(const bf16x8*)(Ag0 + off);
      ra1 = *(const bf16x8*)(Ag1 + off);
      rb0 = *(const bf16x8*)(Bg0 + off);
      rb1 = *(const bf16x8*)(Bg1 + off);
    }
    bf16x8 af[4], bfr[4];
#pragma unroll
    for (int mi = 0; mi < 4; ++mi)
      af[mi] = *(const bf16x8*)&As[(wr * 64 + mi * 16 + t) * 40 + g * 8];
#pragma unroll
    for (int ni = 0; ni < 4; ++ni)
      bfr[ni] = *(const bf16x8*)&Bs[(wc * 64 + ni * 16 + t) * 40 + g * 8];
#pragma unroll
    for (int mi = 0; mi < 4; ++mi)
#pragma unroll
      for (int ni = 0; ni < 4; ++ni)
        acc[mi][ni] = MFMA16(af[mi], bfr[ni], acc[mi][ni]);
  }
}

// ---------------- QKV projection ----------------
__global__ __launch_bounds__(256) void k_gemm_qkv(
    const unsigned short* __restrict__ Xb,
    const unsigned short* __restrict__ Wqt, const unsigned short* __restrict__ Wkt,
    const unsigned short* __restrict__ Wvt,
    unsigned short* __restrict__ Qb, unsigned short* __restrict__ Kb,
    unsigned short* __restrict__ Vt) {
  __shared__ alignas(16) unsigned short As[128 * 40];
  __shared__ alignas(16) unsigned short Bs[128 * 40];
  int z = blockIdx.z;
  const unsigned short* Bt = (z == 0) ? Wqt : (z == 1) ? Wkt : Wvt;
  int tm = (blockIdx.x >> 3) * 128, tn = (blockIdx.x & 7) * 128;
  f32x4 acc[4][4];
  gemm_tile_core(Xb, Bt, DMODEL, tm, tn, As, Bs, acc);

  const int lane = threadIdx.x & 63, w = threadIdx.x >> 6;
  const int wr = w >> 1, wc = w & 1, g = lane >> 4, t = lane & 15;
  if (z < 2) {
    unsigned short* O = (z == 0) ? Qb : Kb;
#pragma unroll
    for (int mi = 0; mi < 4; ++mi)
#pragma unroll
      for (int ni = 0; ni < 4; ++ni)
#pragma unroll
        for (int r = 0; r < 4; ++r) {
          int m = tm + wr * 64 + mi * 16 + g * 4 + r;
          int n = tn + wc * 64 + ni * 16 + t;
          int b = m >> 10, s = m & 1023, h = n >> 6, d = n & 63;
          O[((size_t)((b * 16 + h) * 1024 + s)) * 64 + d] = f2bf(acc[mi][ni][r]);
        }
  } else {
#pragma unroll
    for (int mi = 0; mi < 4; ++mi)
#pragma unroll
      for (int ni = 0; ni < 4; ++ni) {
        int m0 = tm + wr * 64 + mi * 16 + g * 4;
        int n = tn + wc * 64 + ni * 16 + t;
        int b = m0 >> 10, s0 = m0 & 1023, h = n >> 6, d = n & 63;
        ushort4v pk;
#pragma unroll
        for (int r = 0; r < 4; ++r) pk[r] = f2bf(acc[mi][ni][r]);
        *(ushort4v*)&Vt[((size_t)((b * 16 + h) * 64 + d) * 1024) + s0] = pk;
      }
  }
}

// ---------------- flash attention ----------------
// grid: BH*8 blocks; block 256 = 4 waves; wave handles 32 q-rows; k-tiles of 64.
__global__ __launch_bounds__(256) void k_attn(
    const unsigned short* __restrict__ Qb, const unsigned short* __restrict__ Kb,
    const unsigned short* __restrict__ Vt, const float* __restrict__ bt,
    unsigned short* __restrict__ ctx) {
  __shared__ alignas(16) unsigned short P_lds[4][32][72];  // per-wave, padded (144B rows, 16B aligned)
  __shared__ alignas(16) float Lb[2048];                   // bias row (log2e domain)
  const int bh = blockIdx.x >> 3, qb = blockIdx.x & 7;
  const int h = bh & 15, b = bh >> 4;
  const int lane = threadIdx.x & 63, w = threadIdx.x >> 6;
  const int g = lane >> 4, t = lane & 15;
  const int q0 = qb * 128 + w * 32;

  // stage bias row h into LDS (2048 f32 = 8KB)
  {
    const float4* src = (const float4*)(bt + (size_t)h * 2048);
    float4* dst = (float4*)Lb;
    dst[threadIdx.x] = src[threadIdx.x];
    dst[threadIdx.x + 256] = src[threadIdx.x + 256];
  }

  const unsigned short* Qp = Qb + (size_t)bh * SLEN * 64;
  const unsigned short* Kp = Kb + (size_t)bh * SLEN * 64;
  const unsigned short* Vp = Vt + (size_t)bh * 64 * SLEN;

  // Q fragments (A layout)
  bf16x8 aq[2][2];
#pragma unroll
  for (int mi = 0; mi < 2; ++mi)
#pragma unroll
    for (int kk = 0; kk < 2; ++kk)
      aq[mi][kk] = *(const bf16x8*)(Qp + (size_t)(q0 + mi * 16 + t) * 64 + kk * 32 + g * 8);

  f32x4 o[2][4];
  float mrow[2][4], lrow[2][4];
  f32x4 z = {0.f, 0.f, 0.f, 0.f};
#pragma unroll
  for (int mi = 0; mi < 2; ++mi) {
#pragma unroll
    for (int dj = 0; dj < 4; ++dj) o[mi][dj] = z;
#pragma unroll
    for (int r = 0; r < 4; ++r) { mrow[mi][r] = -INFINITY; lrow[mi][r] = 0.f; }
  }

  __syncthreads();
  const float cpos = Lb[1023 + 91];  // saturated bucket, rel >= 91 (log2e domain)
  const float cneg = Lb[1023 - 91];  // saturated bucket, rel <= -91

  // prologue: K fragments for kt=0
  bf16x8 bk[4][2];
#pragma unroll
  for (int nj = 0; nj < 4; ++nj)
#pragma unroll
    for (int kk = 0; kk < 2; ++kk)
      bk[nj][kk] = *(const bf16x8*)(Kp + (size_t)(nj * 16 + t) * 64 + kk * 32 + g * 8);

  for (int kt = 0; kt < 16; ++kt) {
    const int kbase = kt * 64;

    // V fragments for this tile (consumed at the end; latency hidden under QK+softmax)
    bf16x8 bv[4][2];
#pragma unroll
    for (int dj = 0; dj < 4; ++dj)
#pragma unroll
      for (int kk = 0; kk < 2; ++kk)
        bv[dj][kk] = *(const bf16x8*)(Vp + (size_t)(dj * 16 + t) * SLEN + kbase + kk * 32 + g * 8);

    // QK^T
    f32x4 s[2][4];
#pragma unroll
    for (int mi = 0; mi < 2; ++mi)
#pragma unroll
      for (int nj = 0; nj < 4; ++nj) {
        f32x4 a0 = MFMA16(aq[mi][0], bk[nj][0], z);
        s[mi][nj] = MFMA16(aq[mi][1], bk[nj][1], a0);
      }

    // prefetch next K tile into the (now dead) bk regs
    if (kt != 15) {
      const int kb2 = kbase + 64;
#pragma unroll
      for (int nj = 0; nj < 4; ++nj)
#pragma unroll
        for (int kk = 0; kk < 2; ++kk)
          bk[nj][kk] = *(const bf16x8*)(Kp + (size_t)(kb2 + nj * 16 + t) * 64 + kk * 32 + g * 8);
    }

    // bias (log2e domain): far tiles use saturated constant; near tiles gather from LDS
    const bool farp = (kbase >= q0 + 122);       // min rel = kbase-(q0+31) >= 91
    const bool farn = (kbase + 154 <= q0);       // max rel = kbase+63-q0 <= -91
    if (farp || farn) {
      const float c = farp ? cpos : cneg;
#pragma unroll
      for (int mi = 0; mi < 2; ++mi)
#pragma unroll
        for (int nj = 0; nj < 4; ++nj)
#pragma unroll
          for (int r = 0; r < 4; ++r)
            s[mi][nj][r] = fmaf(s[mi][nj][r], LOG2E, c);
    } else {
      const int base = kbase - q0 + 1023 + t - g * 4;
#pragma unroll
      for (int mi = 0; mi < 2; ++mi)
#pragma unroll
        for (int nj = 0; nj < 4; ++nj)
#pragma unroll
          for (int r = 0; r < 4; ++r)
            s[mi][nj][r] = fmaf(s[mi][nj][r], LOG2E, Lb[base + nj * 16 - mi * 16 - r]);
    }

    // online softmax in log2 domain
#pragma unroll
    for (int mi = 0; mi < 2; ++mi)
#pragma unroll
      for (int r = 0; r < 4; ++r) {
        float vm = fmaxf(fmaxf(s[mi][0][r], s[mi][1][r]), fmaxf(s[mi][2][r], s[mi][3][r]));
        vm = fmaxf(vm, __shfl_xor(vm, 1));
        vm = fmaxf(vm, __shfl_xor(vm, 2));
        vm = fmaxf(vm, __shfl_xor(vm, 4));
        vm = fmaxf(vm, __shfl_xor(vm, 8));
        float mn = fmaxf(mrow[mi][r], vm);
        float sc = fast_exp2(mrow[mi][r] - mn);
        float ls = 0.f;
#pragma unroll
        for (int nj = 0; nj < 4; ++nj) {
          float pv = fast_exp2(s[mi][nj][r] - mn);
          s[mi][nj][r] = pv;
          ls += pv;
        }
        lrow[mi][r] = fmaf(lrow[mi][r], sc, ls);
        mrow[mi][r] = mn;
#pragma unroll
        for (int dj = 0; dj < 4; ++dj) o[mi][dj][r] *= sc;
      }

    // P (C-layout) -> LDS -> A-layout fragments
#pragma unroll
    for (int mi = 0; mi < 2; ++mi)
#pragma unroll
      for (int nj = 0; nj < 4; ++nj)
#pragma unroll
        for (int r = 0; r < 4; ++r)
          P_lds[w][mi * 16 + g * 4 + r][nj * 16 + t] = f2bf(s[mi][nj][r]);

    bf16x8 pa[2][2];
#pragma unroll
    for (int mi = 0; mi < 2; ++mi)
#pragma unroll
      for (int kk = 0; kk < 2; ++kk)
        pa[mi][kk] = *(const bf16x8*)&P_lds[w][mi * 16 + t][kk * 32 + g * 8];

#pragma unroll
    for (int mi = 0; mi < 2; ++mi)
#pragma unroll
      for (int dj = 0; dj < 4; ++dj) {
        o[mi][dj] = MFMA16(pa[mi][0], bv[dj][0], o[mi][dj]);
        o[mi][dj] = MFMA16(pa[mi][1], bv[dj][1], o[mi][dj]);
      }
  }

  // finalize
  float inv[2][4];
#pragma unroll
  for (int mi = 0; mi < 2; ++mi)
#pragma unroll
    for (int r = 0; r < 4; ++r) {
      float lv = lrow[mi][r];
      lv += __shfl_xor(lv, 1);
      lv += __shfl_xor(lv, 2);
      lv += __shfl_xor(lv, 4);
      lv += __shfl_xor(lv, 8);
      inv[mi][r] = 1.0f / lv;
    }
#pragma unroll
  for (int mi = 0; mi < 2; ++mi)
#pragma unroll
    for (int dj = 0; dj < 4; ++dj)
#pragma unroll
      for (int r = 0; r < 4; ++r) {
        int qq = q0 + mi * 16 + g * 4 + r;
        int d = dj * 16 + t;
        ctx[((size_t)(b * 1024 + qq)) * 1024 + h * 64 + d] = f2bf(o[mi][dj][r] * inv[mi][r]);
      }
}

// ---------------- output projection: out = ctx @ wo (f32 out) ----------------
__global__ __launch_bounds__(256) void k_gemm_out(
    const unsigned short* __restrict__ Cb, const unsigned short* __restrict__ Wot,
    float* __restrict__ out) {
  __shared__ alignas(16) unsigned short As[128 * 40];
  __shared__ alignas(16) unsigned short Bs[128 * 40];
  int tm = (blockIdx.x >> 3) * 128, tn = (blockIdx.x & 7) * 128;
  f32x4 acc[4][4];
  gemm_tile_core(Cb, Wot, DMODEL, tm, tn, As, Bs, acc);

  const int lane = threadIdx.x & 63, w = threadIdx.x >> 6;
  const int wr = w >> 1, wc = w & 1, g = lane >> 4, t = lane & 15;
#pragma unroll
  for (int mi = 0; mi < 4; ++mi)
#pragma unroll
    for (int ni = 0; ni < 4; ++ni)
#pragma unroll
      for (int r = 0; r < 4; ++r) {
        int m = tm + wr * 64 + mi * 16 + g * 4 + r;
        int n = tn + wc * 64 + ni * 16 + t;
        out[(size_t)m * DMODEL + n] = acc[mi][ni][r];
      }
}

extern "C" void kernel_launch(void* const* d_in, const int* in_sizes, int n_in,
                              void* d_out, int out_size, void* d_ws, size_t ws_size,
                              hipStream_t stream) {
  const float* hs = (const float*)d_in[0];
  const float* wq = (const float*)d_in[1];
  const float* wk = (const float*)d_in[2];
  const float* wv = (const float*)d_in[3];
  const float* wo = (const float*)d_in[4];
  const float* rb = (const float*)d_in[5];

  char* ws = (char*)d_ws;
  unsigned short* Xb  = (unsigned short*)(ws + 0);          // 16 MB
  unsigned short* Wqt = (unsigned short*)(ws + 16777216);   // 2 MB
  unsigned short* Wkt = (unsigned short*)(ws + 18874368);
  unsigned short* Wvt = (unsigned short*)(ws + 20971520);
  unsigned short* Wot = (unsigned short*)(ws + 23068672);
  unsigned short* Qb  = (unsigned short*)(ws + 25165824);   // 16 MB
  unsigned short* Kb  = (unsigned short*)(ws + 41943040);   // 16 MB
  unsigned short* Vt  = (unsigned short*)(ws + 58720256);   // 16 MB
  unsigned short* Cb  = (unsigned short*)(ws + 75497472);   // 16 MB
  float* bt           = (float*)(ws + 92274688);            // 128 KB

  k_convert_x<<<4096, 256, 0, stream>>>(hs, Xb, NROWS * DMODEL);
  k_transpose_w<<<dim3(1024, 1, 4), 256, 0, stream>>>(wq, wk, wv, wo, Wqt, Wkt, Wvt, Wot);
  k_bias_table<<<128, 256, 0, stream>>>(rb, bt);
  k_gemm_qkv<<<dim3(512, 1, 3), 256, 0, stream>>>(Xb, Wqt, Wkt, Wvt, Qb, Kb, Vt);
  k_attn<<<1024, 256, 0, stream>>>(Qb, Kb, Vt, bt, Cb);
  k_gemm_out<<<512, 256, 0, stream>>>(Cb, Wot, (float*)d_out);
}

// Round 3
// 252.088 us; speedup vs baseline: 1.2380x; 1.0572x over previous
//
#include <hip/hip_runtime.h>
#include <stdint.h>

typedef __attribute__((ext_vector_type(8))) short bf16x8;
typedef __attribute__((ext_vector_type(4))) float f32x4;
typedef __attribute__((ext_vector_type(16))) float f32x16;
typedef __attribute__((ext_vector_type(8))) unsigned short ushort8;
typedef __attribute__((ext_vector_type(4))) unsigned short ushort4v;

#define MFMA16(a, b, c) __builtin_amdgcn_mfma_f32_16x16x32_bf16((a), (b), (c), 0, 0, 0)
#define MFMA32(a, b, c) __builtin_amdgcn_mfma_f32_32x32x16_bf16((a), (b), (c), 0, 0, 0)

// B=8, S=1024, D=1024, H=16, DK=64
#define SLEN 1024
#define NHEAD 16
#define HDIM 64
#define DMODEL 1024
#define NROWS 8192  // B*S
#define LOG2E 1.44269504088896340736f

__device__ __forceinline__ unsigned short f2bf(float f) {
  unsigned int u = __float_as_uint(f);
  u += 0x7FFFu + ((u >> 16) & 1u);   // RNE
  return (unsigned short)(u >> 16);
}

__device__ __forceinline__ float fast_exp2(float x) {
#if __has_builtin(__builtin_amdgcn_exp2f)
  return __builtin_amdgcn_exp2f(x);
#else
  float r; asm("v_exp_f32 %0, %1" : "=v"(r) : "v"(x)); return r;
#endif
}

__device__ __forceinline__ unsigned int cvt_pk_bf16(float lo, float hi) {
  unsigned int r;
  asm("v_cvt_pk_bf16_f32 %0, %1, %2" : "=v"(r) : "v"(lo), "v"(hi));
  return r;
}

// ---------------- convert hidden_states f32 -> bf16 ----------------
__global__ __launch_bounds__(256) void k_convert_x(const float* __restrict__ x,
                                                   unsigned short* __restrict__ xb, int n) {
  int i = blockIdx.x * 256 + threadIdx.x;
  int idx = i * 8;
  if (idx >= n) return;
  float4 a = *(const float4*)(x + idx);
  float4 b = *(const float4*)(x + idx + 4);
  ushort8 o;
  o[0] = f2bf(a.x); o[1] = f2bf(a.y); o[2] = f2bf(a.z); o[3] = f2bf(a.w);
  o[4] = f2bf(b.x); o[5] = f2bf(b.y); o[6] = f2bf(b.z); o[7] = f2bf(b.w);
  *(ushort8*)(xb + idx) = o;
}

// ---------------- transpose + convert weights: W[K][N] f32 -> Wt[N][K] bf16 ----------------
__global__ __launch_bounds__(256) void k_transpose_w(
    const float* __restrict__ w0, const float* __restrict__ w1,
    const float* __restrict__ w2, const float* __restrict__ w3,
    unsigned short* __restrict__ o0, unsigned short* __restrict__ o1,
    unsigned short* __restrict__ o2, unsigned short* __restrict__ o3) {
  int z = blockIdx.z;
  const float* w = (z == 0) ? w0 : (z == 1) ? w1 : (z == 2) ? w2 : w3;
  unsigned short* o = (z == 0) ? o0 : (z == 1) ? o1 : (z == 2) ? o2 : o3;
  __shared__ unsigned short tile[32][33];
  int bx = blockIdx.x & 31, by = blockIdx.x >> 5;
  int tid = threadIdx.x;
#pragma unroll
  for (int p = 0; p < 4; ++p) {
    int idx = tid + p * 256;
    int r = idx >> 5, c = idx & 31;
    tile[r][c] = f2bf(w[(size_t)(by * 32 + r) * DMODEL + bx * 32 + c]);
  }
  __syncthreads();
#pragma unroll
  for (int p = 0; p < 4; ++p) {
    int idx = tid + p * 256;
    int r = idx >> 5, c = idx & 31;
    o[(size_t)(bx * 32 + r) * DMODEL + by * 32 + c] = tile[c][r];
  }
}

// ---------------- relative-position bias table: bt[h][rel+1023] * log2e, rel=k-q ----------------
__global__ __launch_bounds__(256) void k_bias_table(const float* __restrict__ rel_bias,
                                                    float* __restrict__ bt) {
  int i = blockIdx.x * 256 + threadIdx.x;
  if (i >= NHEAD * 2047) return;
  int h = i / 2047, rdx = i % 2047;
  int rel = rdx - 1023;
  int rb = (rel > 0) ? 16 : 0;
  int rp = (rel < 0) ? -rel : rel;
  int bucket;
  if (rp < 8) {
    bucket = rb + rp;
  } else {
    // large = 8 + floor(2*log2(rp)) - 6, capped at 15. Integer-exact via clz+square.
    int large;
    if (rp >= 91) {
      large = 15;
    } else {
      int nb = 31 - __clz(rp);
      long long sq = (long long)rp * rp;
      int f2 = 2 * nb + ((sq >= (1LL << (2 * nb + 1))) ? 1 : 0);
      large = 8 + (f2 - 6);
      if (large > 15) large = 15;
    }
    bucket = rb + large;
  }
  bt[h * 2048 + rdx] = rel_bias[bucket * 16 + h] * LOG2E;  // log2e domain
}

// ---------------- shared GEMM core: C[128x128] = A[M][K] * Bt[N][K]^T ----------------
__device__ __forceinline__ void gemm_tile_core(const unsigned short* __restrict__ A,
                                               const unsigned short* __restrict__ Bt,
                                               int K, int tm, int tn,
                                               unsigned short* As, unsigned short* Bs,
                                               f32x4 acc[4][4]) {
  const int tid = threadIdx.x;
  const int lane = tid & 63;
  const int w = tid >> 6;
  const int wr = w >> 1, wc = w & 1;
  const int g = lane >> 4, t = lane & 15;
  const int NKT = K >> 5;

  const int r0 = tid >> 2, kc = (tid & 3) * 8;
  const int r1 = r0 + 64;
  const unsigned short* Ag0 = A + (size_t)(tm + r0) * K + kc;
  const unsigned short* Ag1 = A + (size_t)(tm + r1) * K + kc;
  const unsigned short* Bg0 = Bt + (size_t)(tn + r0) * K + kc;
  const unsigned short* Bg1 = Bt + (size_t)(tn + r1) * K + kc;

  f32x4 z = {0.f, 0.f, 0.f, 0.f};
#pragma unroll
  for (int mi = 0; mi < 4; ++mi)
#pragma unroll
    for (int ni = 0; ni < 4; ++ni) acc[mi][ni] = z;

  bf16x8 ra0 = *(const bf16x8*)(Ag0);
  bf16x8 ra1 = *(const bf16x8*)(Ag1);
  bf16x8 rb0 = *(const bf16x8*)(Bg0);
  bf16x8 rb1 = *(const bf16x8*)(Bg1);

  for (int kt = 0; kt < NKT; ++kt) {
    __syncthreads();
    *(bf16x8*)&As[r0 * 40 + kc] = ra0;
    *(bf16x8*)&As[r1 * 40 + kc] = ra1;
    *(bf16x8*)&Bs[r0 * 40 + kc] = rb0;
    *(bf16x8*)&Bs[r1 * 40 + kc] = rb1;
    __syncthreads();
    if (kt + 1 < NKT) {
      int off = (kt + 1) * 32;
      ra0 = *(const bf16x8*)(Ag0 + off);
      ra1 = *(const bf16x8*)(Ag1 + off);
      rb0 = *(const bf16x8*)(Bg0 + off);
      rb1 = *(const bf16x8*)(Bg1 + off);
    }
    bf16x8 af[4], bfr[4];
#pragma unroll
    for (int mi = 0; mi < 4; ++mi)
      af[mi] = *(const bf16x8*)&As[(wr * 64 + mi * 16 + t) * 40 + g * 8];
#pragma unroll
    for (int ni = 0; ni < 4; ++ni)
      bfr[ni] = *(const bf16x8*)&Bs[(wc * 64 + ni * 16 + t) * 40 + g * 8];
#pragma unroll
    for (int mi = 0; mi < 4; ++mi)
#pragma unroll
      for (int ni = 0; ni < 4; ++ni)
        acc[mi][ni] = MFMA16(af[mi], bfr[ni], acc[mi][ni]);
  }
}

// ---------------- QKV projection ----------------
__global__ __launch_bounds__(256) void k_gemm_qkv(
    const unsigned short* __restrict__ Xb,
    const unsigned short* __restrict__ Wqt, const unsigned short* __restrict__ Wkt,
    const unsigned short* __restrict__ Wvt,
    unsigned short* __restrict__ Qb, unsigned short* __restrict__ Kb,
    unsigned short* __restrict__ Vt) {
  __shared__ alignas(16) unsigned short As[128 * 40];
  __shared__ alignas(16) unsigned short Bs[128 * 40];
  int z = blockIdx.z;
  const unsigned short* Bt = (z == 0) ? Wqt : (z == 1) ? Wkt : Wvt;
  int tm = (blockIdx.x >> 3) * 128, tn = (blockIdx.x & 7) * 128;
  f32x4 acc[4][4];
  gemm_tile_core(Xb, Bt, DMODEL, tm, tn, As, Bs, acc);

  const int lane = threadIdx.x & 63, w = threadIdx.x >> 6;
  const int wr = w >> 1, wc = w & 1, g = lane >> 4, t = lane & 15;
  if (z < 2) {
    unsigned short* O = (z == 0) ? Qb : Kb;
#pragma unroll
    for (int mi = 0; mi < 4; ++mi)
#pragma unroll
      for (int ni = 0; ni < 4; ++ni)
#pragma unroll
        for (int r = 0; r < 4; ++r) {
          int m = tm + wr * 64 + mi * 16 + g * 4 + r;
          int n = tn + wc * 64 + ni * 16 + t;
          int b = m >> 10, s = m & 1023, h = n >> 6, d = n & 63;
          O[((size_t)((b * 16 + h) * 1024 + s)) * 64 + d] = f2bf(acc[mi][ni][r]);
        }
  } else {
#pragma unroll
    for (int mi = 0; mi < 4; ++mi)
#pragma unroll
      for (int ni = 0; ni < 4; ++ni) {
        int m0 = tm + wr * 64 + mi * 16 + g * 4;
        int n = tn + wc * 64 + ni * 16 + t;
        int b = m0 >> 10, s0 = m0 & 1023, h = n >> 6, d = n & 63;
        ushort4v pk;
#pragma unroll
        for (int r = 0; r < 4; ++r) pk[r] = f2bf(acc[mi][ni][r]);
        *(ushort4v*)&Vt[((size_t)((b * 16 + h) * 64 + d) * 1024) + s0] = pk;
      }
  }
}

// ---------------- flash attention (swapped QK^T, 32x32 MFMA, in-register softmax) ----------------
// grid: BH*8 blocks; block 256 = 4 waves; wave handles 32 q-rows; k-tiles of 32.
// S[k][q] layout: q = lane&31 (lane-local softmax); k over regs: (r&3)+8*(r>>2)+4*hi.
__global__ __launch_bounds__(256) void k_attn(
    const unsigned short* __restrict__ Qb, const unsigned short* __restrict__ Kb,
    const unsigned short* __restrict__ Vt, const float* __restrict__ bt,
    unsigned short* __restrict__ ctx) {
  __shared__ alignas(16) float Lb[2048];   // bias row (log2e domain)
  __shared__ float sred[4][32];            // per-wave q->reg redistribution
  const int bh = blockIdx.x >> 3, qb = blockIdx.x & 7;
  const int h = bh & 15, b = bh >> 4;
  const int lane = threadIdx.x & 63, w = threadIdx.x >> 6;
  const int ql = lane & 31, hi = lane >> 5;
  const int q0 = qb * 128 + w * 32;
  const int q = q0 + ql;

  // stage bias row h into LDS
  {
    const float4* src = (const float4*)(bt + (size_t)h * 2048);
    float4* dst = (float4*)Lb;
    dst[threadIdx.x] = src[threadIdx.x];
    dst[threadIdx.x + 256] = src[threadIdx.x + 256];
  }

  const unsigned short* Qp = Qb + (size_t)bh * SLEN * 64;
  const unsigned short* Kp = Kb + (size_t)bh * SLEN * 64;
  const unsigned short* Vp = Vt + (size_t)bh * 64 * SLEN;

  // Q as B-operand: col=lane&31=q, k-dim (d) contiguous 8 at hi*8 within each 16-chunk
  bf16x8 bq[4];
#pragma unroll
  for (int c = 0; c < 4; ++c)
    bq[c] = *(const bf16x8*)(Qp + (size_t)q * 64 + c * 16 + hi * 8);

  const f32x16 z16 = {0.f,0.f,0.f,0.f,0.f,0.f,0.f,0.f,0.f,0.f,0.f,0.f,0.f,0.f,0.f,0.f};
  f32x16 o0 = z16, o1 = z16;   // O[q-rows over regs][d = dh*32 + lane&31]
  float m = -INFINITY, l = 0.f;

  __syncthreads();
  const float cpos = Lb[1023 + 91], cneg = Lb[1023 - 91];  // saturated buckets

  // K as A-operand prologue (kt=0): row=lane&31=key, d contiguous 8 at hi*8
  bf16x8 ak[4];
#pragma unroll
  for (int c = 0; c < 4; ++c)
    ak[c] = *(const bf16x8*)(Kp + (size_t)ql * 64 + c * 16 + hi * 8);

#pragma unroll 1
  for (int kt = 0; kt < 32; ++kt) {
    const int kbase = kt * 32;

    // V B-operand frags: bv{chunk}{dhalf}; consumed after softmax (latency hidden)
    bf16x8 bv00 = *(const bf16x8*)(Vp + (size_t)ql * SLEN + kbase + hi * 8);
    bf16x8 bv01 = *(const bf16x8*)(Vp + (size_t)(32 + ql) * SLEN + kbase + hi * 8);
    bf16x8 bv10 = *(const bf16x8*)(Vp + (size_t)ql * SLEN + kbase + 16 + hi * 8);
    bf16x8 bv11 = *(const bf16x8*)(Vp + (size_t)(32 + ql) * SLEN + kbase + 16 + hi * 8);

    // QK^T: S[k][q] = sum_d K[k][d] Q[q][d]
    f32x16 s = z16;
    __builtin_amdgcn_s_setprio(1);
    s = MFMA32(ak[0], bq[0], s);
    s = MFMA32(ak[1], bq[1], s);
    s = MFMA32(ak[2], bq[2], s);
    s = MFMA32(ak[3], bq[3], s);
    __builtin_amdgcn_s_setprio(0);

    // prefetch next K tile (regs dead after QK)
    if (kt != 31) {
#pragma unroll
      for (int c = 0; c < 4; ++c)
        ak[c] = *(const bf16x8*)(Kp + (size_t)(kbase + 32 + ql) * 64 + c * 16 + hi * 8);
    }

    // bias add in log2 domain
    const bool farp = (kbase >= q0 + 122);   // min rel >= 91
    const bool farn = (kbase + 122 <= q0);   // max rel <= -91
    if (farp || farn) {
      const float c = farp ? cpos : cneg;
#pragma unroll
      for (int r = 0; r < 16; ++r) s[r] = fmaf(s[r], LOG2E, c);
    } else {
      const int base = kbase - q + 1023 + hi * 4;
#pragma unroll
      for (int r = 0; r < 16; ++r)
        s[r] = fmaf(s[r], LOG2E, Lb[base + (r & 3) + 8 * (r >> 2)]);
    }

    // tile max for my q (in-register + one cross-half exchange)
    float vm = s[0];
#pragma unroll
    for (int r = 1; r < 16; ++r) vm = fmaxf(vm, s[r]);
    vm = fmaxf(vm, __shfl_xor(vm, 32));

    // defer-max rescale (THR=8 in log2 domain; algebraically exact)
    if (__any(vm > m + 8.0f)) {
      const float mn = fmaxf(m, vm);
      const float sc = fast_exp2(m - mn);   // exp2(-inf)=0 handles first tile
      m = mn;
      l *= sc;
      sred[w][ql] = sc;                     // redistribute per-q sc to O's reg layout
      __builtin_amdgcn_wave_barrier();
#pragma unroll
      for (int r = 0; r < 16; ++r) {
        const float sr = sred[w][(r & 3) + 8 * (r >> 2) + hi * 4];
        o0[r] *= sr; o1[r] *= sr;
      }
      __builtin_amdgcn_wave_barrier();
    }

    // P = exp2(s - m), row sum
    float p[16];
    float ls = 0.f;
#pragma unroll
    for (int r = 0; r < 16; ++r) { p[r] = fast_exp2(s[r] - m); ls += p[r]; }
    l += ls + __shfl_xor(ls, 32);

    // pack P into PV A-operand frags (k contiguous per lane via cross-half exchange)
    unsigned int wv[8], xv[8];
#pragma unroll
    for (int i = 0; i < 8; ++i) wv[i] = cvt_pk_bf16(p[2 * i], p[2 * i + 1]);
#pragma unroll
    for (int i = 0; i < 8; ++i) xv[i] = __shfl_xor(wv[i], 32);
    union { unsigned int u[4]; bf16x8 v; } pa0, pa1;
    pa0.u[0] = hi ? xv[2] : wv[0];
    pa0.u[1] = hi ? xv[3] : wv[1];
    pa0.u[2] = hi ? wv[2] : xv[0];
    pa0.u[3] = hi ? wv[3] : xv[1];
    pa1.u[0] = hi ? xv[6] : wv[4];
    pa1.u[1] = hi ? xv[7] : wv[5];
    pa1.u[2] = hi ? wv[6] : xv[4];
    pa1.u[3] = hi ? wv[7] : xv[5];

    // PV: O[q][d] += P[q][k] V[k][d]
    __builtin_amdgcn_s_setprio(1);
    o0 = MFMA32(pa0.v, bv00, o0);
    o0 = MFMA32(pa1.v, bv10, o0);
    o1 = MFMA32(pa0.v, bv01, o1);
    o1 = MFMA32(pa1.v, bv11, o1);
    __builtin_amdgcn_s_setprio(0);
  }

  // finalize: redistribute 1/l to O layout, scale, store
  const float inv = 1.0f / l;
  sred[w][ql] = inv;
  __builtin_amdgcn_wave_barrier();
#pragma unroll
  for (int r = 0; r < 16; ++r) {
    const float ir = sred[w][(r & 3) + 8 * (r >> 2) + hi * 4];
    const int qq = q0 + (r & 3) + 8 * (r >> 2) + hi * 4;
    const size_t base = ((size_t)(b * 1024 + qq)) * 1024 + h * 64 + ql;
    ctx[base] = f2bf(o0[r] * ir);
    ctx[base + 32] = f2bf(o1[r] * ir);
  }
}

// ---------------- output projection: out = ctx @ wo (f32 out) ----------------
__global__ __launch_bounds__(256) void k_gemm_out(
    const unsigned short* __restrict__ Cb, const unsigned short* __restrict__ Wot,
    float* __restrict__ out) {
  __shared__ alignas(16) unsigned short As[128 * 40];
  __shared__ alignas(16) unsigned short Bs[128 * 40];
  int tm = (blockIdx.x >> 3) * 128, tn = (blockIdx.x & 7) * 128;
  f32x4 acc[4][4];
  gemm_tile_core(Cb, Wot, DMODEL, tm, tn, As, Bs, acc);

  const int lane = threadIdx.x & 63, w = threadIdx.x >> 6;
  const int wr = w >> 1, wc = w & 1, g = lane >> 4, t = lane & 15;
#pragma unroll
  for (int mi = 0; mi < 4; ++mi)
#pragma unroll
    for (int ni = 0; ni < 4; ++ni)
#pragma unroll
      for (int r = 0; r < 4; ++r) {
        int m = tm + wr * 64 + mi * 16 + g * 4 + r;
        int n = tn + wc * 64 + ni * 16 + t;
        out[(size_t)m * DMODEL + n] = acc[mi][ni][r];
      }
}

extern "C" void kernel_launch(void* const* d_in, const int* in_sizes, int n_in,
                              void* d_out, int out_size, void* d_ws, size_t ws_size,
                              hipStream_t stream) {
  const float* hs = (const float*)d_in[0];
  const float* wq = (const float*)d_in[1];
  const float* wk = (const float*)d_in[2];
  const float* wv = (const float*)d_in[3];
  const float* wo = (const float*)d_in[4];
  const float* rb = (const float*)d_in[5];

  char* ws = (char*)d_ws;
  unsigned short* Xb  = (unsigned short*)(ws + 0);          // 16 MB
  unsigned short* Wqt = (unsigned short*)(ws + 16777216);   // 2 MB
  unsigned short* Wkt = (unsigned short*)(ws + 18874368);
  unsigned short* Wvt = (unsigned short*)(ws + 20971520);
  unsigned short* Wot = (unsigned short*)(ws + 23068672);
  unsigned short* Qb  = (unsigned short*)(ws + 25165824);   // 16 MB
  unsigned short* Kb  = (unsigned short*)(ws + 41943040);   // 16 MB
  unsigned short* Vt  = (unsigned short*)(ws + 58720256);   // 16 MB
  unsigned short* Cb  = (unsigned short*)(ws + 75497472);   // 16 MB
  float* bt           = (float*)(ws + 92274688);            // 128 KB

  k_convert_x<<<4096, 256, 0, stream>>>(hs, Xb, NROWS * DMODEL);
  k_transpose_w<<<dim3(1024, 1, 4), 256, 0, stream>>>(wq, wk, wv, wo, Wqt, Wkt, Wvt, Wot);
  k_bias_table<<<128, 256, 0, stream>>>(rb, bt);
  k_gemm_qkv<<<dim3(512, 1, 3), 256, 0, stream>>>(Xb, Wqt, Wkt, Wvt, Qb, Kb, Vt);
  k_attn<<<1024, 256, 0, stream>>>(Qb, Kb, Vt, bt, Cb);
  k_gemm_out<<<512, 256, 0, stream>>>(Cb, Wot, (float*)d_out);
}

// Round 6
// 211.987 us; speedup vs baseline: 1.4722x; 1.1892x over previous
//
#include <hip/hip_runtime.h>
#include <stdint.h>

typedef __attribute__((ext_vector_type(8))) short bf16x8;
typedef __attribute__((ext_vector_type(4))) float f32x4;
typedef __attribute__((ext_vector_type(16))) float f32x16;
typedef __attribute__((ext_vector_type(8))) unsigned short ushort8;
typedef __attribute__((ext_vector_type(4))) unsigned short ushort4v;

#define MFMA16(a, b, c) __builtin_amdgcn_mfma_f32_16x16x32_bf16((a), (b), (c), 0, 0, 0)
#define MFMA32(a, b, c) __builtin_amdgcn_mfma_f32_32x32x16_bf16((a), (b), (c), 0, 0, 0)

// B=8, S=1024, D=1024, H=16, DK=64
#define SLEN 1024
#define NHEAD 16
#define HDIM 64
#define DMODEL 1024
#define NROWS 8192  // B*S
#define LOG2E 1.44269504088896340736f

__device__ __forceinline__ unsigned short f2bf(float f) {
  unsigned int u = __float_as_uint(f);
  u += 0x7FFFu + ((u >> 16) & 1u);   // RNE
  return (unsigned short)(u >> 16);
}

__device__ __forceinline__ float fast_exp2(float x) {
#if __has_builtin(__builtin_amdgcn_exp2f)
  return __builtin_amdgcn_exp2f(x);
#else
  float r; asm("v_exp_f32 %0, %1" : "=v"(r) : "v"(x)); return r;
#endif
}

__device__ __forceinline__ unsigned int cvt_pk_bf16(float lo, float hi) {
  unsigned int r;
  asm("v_cvt_pk_bf16_f32 %0, %1, %2" : "=v"(r) : "v"(lo), "v"(hi));
  return r;
}

// async global->LDS, 16B per lane; LDS dest = wave-uniform base + lane*16 (HW).
__device__ __forceinline__ void gload_lds16(const void* g, void* l) {
  __builtin_amdgcn_global_load_lds(
      (const __attribute__((address_space(1))) void*)g,
      (__attribute__((address_space(3))) void*)l, 16, 0, 0);
}

// ---------------- convert hidden_states f32 -> bf16 ----------------
__global__ __launch_bounds__(256) void k_convert_x(const float* __restrict__ x,
                                                   unsigned short* __restrict__ xb, int n) {
  int i = blockIdx.x * 256 + threadIdx.x;
  int idx = i * 8;
  if (idx >= n) return;
  float4 a = *(const float4*)(x + idx);
  float4 b = *(const float4*)(x + idx + 4);
  ushort8 o;
  o[0] = f2bf(a.x); o[1] = f2bf(a.y); o[2] = f2bf(a.z); o[3] = f2bf(a.w);
  o[4] = f2bf(b.x); o[5] = f2bf(b.y); o[6] = f2bf(b.z); o[7] = f2bf(b.w);
  *(ushort8*)(xb + idx) = o;
}

// ---------------- transpose + convert weights: W[K][N] f32 -> Wt[N][K] bf16 ----------------
__global__ __launch_bounds__(256) void k_transpose_w(
    const float* __restrict__ w0, const float* __restrict__ w1,
    const float* __restrict__ w2, const float* __restrict__ w3,
    unsigned short* __restrict__ o0, unsigned short* __restrict__ o1,
    unsigned short* __restrict__ o2, unsigned short* __restrict__ o3) {
  int z = blockIdx.z;
  const float* w = (z == 0) ? w0 : (z == 1) ? w1 : (z == 2) ? w2 : w3;
  unsigned short* o = (z == 0) ? o0 : (z == 1) ? o1 : (z == 2) ? o2 : o3;
  __shared__ unsigned short tile[32][33];
  int bx = blockIdx.x & 31, by = blockIdx.x >> 5;
  int tid = threadIdx.x;
#pragma unroll
  for (int p = 0; p < 4; ++p) {
    int idx = tid + p * 256;
    int r = idx >> 5, c = idx & 31;
    tile[r][c] = f2bf(w[(size_t)(by * 32 + r) * DMODEL + bx * 32 + c]);
  }
  __syncthreads();
#pragma unroll
  for (int p = 0; p < 4; ++p) {
    int idx = tid + p * 256;
    int r = idx >> 5, c = idx & 31;
    o[(size_t)(bx * 32 + r) * DMODEL + by * 32 + c] = tile[c][r];
  }
}

// ---------------- relative-position bias table: bt[h][rel+1023] * log2e, rel=k-q ----------------
__global__ __launch_bounds__(256) void k_bias_table(const float* __restrict__ rel_bias,
                                                    float* __restrict__ bt) {
  int i = blockIdx.x * 256 + threadIdx.x;
  if (i >= NHEAD * 2047) return;
  int h = i / 2047, rdx = i % 2047;
  int rel = rdx - 1023;
  int rb = (rel > 0) ? 16 : 0;
  int rp = (rel < 0) ? -rel : rel;
  int bucket;
  if (rp < 8) {
    bucket = rb + rp;
  } else {
    // large = 8 + floor(2*log2(rp)) - 6, capped at 15. Integer-exact via clz+square.
    int large;
    if (rp >= 91) {
      large = 15;
    } else {
      int nb = 31 - __clz(rp);
      long long sq = (long long)rp * rp;
      int f2 = 2 * nb + ((sq >= (1LL << (2 * nb + 1))) ? 1 : 0);
      large = 8 + (f2 - 6);
      if (large > 15) large = 15;
    }
    bucket = rb + large;
  }
  bt[h * 2048 + rdx] = rel_bias[bucket * 16 + h] * LOG2E;  // log2e domain
}

// ---------------- shared GEMM core: C[128x128] = A[M][K] * Bt[N][K]^T ----------------
__device__ __forceinline__ void gemm_tile_core(const unsigned short* __restrict__ A,
                                               const unsigned short* __restrict__ Bt,
                                               int K, int tm, int tn,
                                               unsigned short* As, unsigned short* Bs,
                                               f32x4 acc[4][4]) {
  const int tid = threadIdx.x;
  const int lane = tid & 63;
  const int w = tid >> 6;
  const int wr = w >> 1, wc = w & 1;
  const int g = lane >> 4, t = lane & 15;
  const int NKT = K >> 5;

  const int r0 = tid >> 2, kc = (tid & 3) * 8;
  const int r1 = r0 + 64;
  const unsigned short* Ag0 = A + (size_t)(tm + r0) * K + kc;
  const unsigned short* Ag1 = A + (size_t)(tm + r1) * K + kc;
  const unsigned short* Bg0 = Bt + (size_t)(tn + r0) * K + kc;
  const unsigned short* Bg1 = Bt + (size_t)(tn + r1) * K + kc;

  f32x4 z = {0.f, 0.f, 0.f, 0.f};
#pragma unroll
  for (int mi = 0; mi < 4; ++mi)
#pragma unroll
    for (int ni = 0; ni < 4; ++ni) acc[mi][ni] = z;

  bf16x8 ra0 = *(const bf16x8*)(Ag0);
  bf16x8 ra1 = *(const bf16x8*)(Ag1);
  bf16x8 rb0 = *(const bf16x8*)(Bg0);
  bf16x8 rb1 = *(const bf16x8*)(Bg1);

  for (int kt = 0; kt < NKT; ++kt) {
    __syncthreads();
    *(bf16x8*)&As[r0 * 40 + kc] = ra0;
    *(bf16x8*)&As[r1 * 40 + kc] = ra1;
    *(bf16x8*)&Bs[r0 * 40 + kc] = rb0;
    *(bf16x8*)&Bs[r1 * 40 + kc] = rb1;
    __syncthreads();
    if (kt + 1 < NKT) {
      int off = (kt + 1) * 32;
      ra0 = *(const bf16x8*)(Ag0 + off);
      ra1 = *(const bf16x8*)(Ag1 + off);
      rb0 = *(const bf16x8*)(Bg0 + off);
      rb1 = *(const bf16x8*)(Bg1 + off);
    }
    bf16x8 af[4], bfr[4];
#pragma unroll
    for (int mi = 0; mi < 4; ++mi)
      af[mi] = *(const bf16x8*)&As[(wr * 64 + mi * 16 + t) * 40 + g * 8];
#pragma unroll
    for (int ni = 0; ni < 4; ++ni)
      bfr[ni] = *(const bf16x8*)&Bs[(wc * 64 + ni * 16 + t) * 40 + g * 8];
#pragma unroll
    for (int mi = 0; mi < 4; ++mi)
#pragma unroll
      for (int ni = 0; ni < 4; ++ni)
        acc[mi][ni] = MFMA16(af[mi], bfr[ni], acc[mi][ni]);
  }
}

// ---------------- QKV projection ----------------
__global__ __launch_bounds__(256) void k_gemm_qkv(
    const unsigned short* __restrict__ Xb,
    const unsigned short* __restrict__ Wqt, const unsigned short* __restrict__ Wkt,
    const unsigned short* __restrict__ Wvt,
    unsigned short* __restrict__ Qb, unsigned short* __restrict__ Kb,
    unsigned short* __restrict__ Vt) {
  __shared__ alignas(16) unsigned short As[128 * 40];
  __shared__ alignas(16) unsigned short Bs[128 * 40];
  int z = blockIdx.z;
  const unsigned short* Bt = (z == 0) ? Wqt : (z == 1) ? Wkt : Wvt;
  int tm = (blockIdx.x >> 3) * 128, tn = (blockIdx.x & 7) * 128;
  f32x4 acc[4][4];
  gemm_tile_core(Xb, Bt, DMODEL, tm, tn, As, Bs, acc);

  const int lane = threadIdx.x & 63, w = threadIdx.x >> 6;
  const int wr = w >> 1, wc = w & 1, g = lane >> 4, t = lane & 15;
  if (z < 2) {
    unsigned short* O = (z == 0) ? Qb : Kb;
#pragma unroll
    for (int mi = 0; mi < 4; ++mi)
#pragma unroll
      for (int ni = 0; ni < 4; ++ni)
#pragma unroll
        for (int r = 0; r < 4; ++r) {
          int m = tm + wr * 64 + mi * 16 + g * 4 + r;
          int n = tn + wc * 64 + ni * 16 + t;
          int b = m >> 10, s = m & 1023, h = n >> 6, d = n & 63;
          O[((size_t)((b * 16 + h) * 1024 + s)) * 64 + d] = f2bf(acc[mi][ni][r]);
        }
  } else {
#pragma unroll
    for (int mi = 0; mi < 4; ++mi)
#pragma unroll
      for (int ni = 0; ni < 4; ++ni) {
        int m0 = tm + wr * 64 + mi * 16 + g * 4;
        int n = tn + wc * 64 + ni * 16 + t;
        int b = m0 >> 10, s0 = m0 & 1023, h = n >> 6, d = n & 63;
        ushort4v pk;
#pragma unroll
        for (int r = 0; r < 4; ++r) pk[r] = f2bf(acc[mi][ni][r]);
        *(ushort4v*)&Vt[((size_t)((b * 16 + h) * 64 + d) * 1024) + s0] = pk;
      }
  }
}

// ---------------- flash attention ----------------
// grid 1024 (XCD-swizzled); block 256 = 4 waves; wave = 32 q-rows.
// KVBLK=64 LDS tiles (double-buffered, global_load_lds, XOR swizzle); compute processes
// each tile as two sequential 32-key halves, op-for-op identical to the R3 kernel.
__global__ __launch_bounds__(256) void k_attn(
    const unsigned short* __restrict__ Qb, const unsigned short* __restrict__ Kb,
    const unsigned short* __restrict__ Vt, const float* __restrict__ bt,
    unsigned short* __restrict__ ctx) {
  __shared__ alignas(16) unsigned short Ks[2][64 * 64];  // [key][d] swizzled, 8KB each
  __shared__ alignas(16) unsigned short Vs[2][64 * 64];  // [d][key] swizzled, 8KB each
  __shared__ alignas(16) float Lb[376];                  // bias, rel in [-186,189], log2e domain
  __shared__ float sred[4][32];

  const int wid = ((blockIdx.x & 7) << 7) | (blockIdx.x >> 3);  // XCD-local head grouping
  const int bh = wid >> 3, qb = wid & 7;
  const int h = bh & 15, b = bh >> 4;
  const int tid = threadIdx.x;
  const int lane = tid & 63, w = tid >> 6;
  const int ql = lane & 31, hi = lane >> 5;
  const int q0 = qb * 128 + w * 32;
  const int q = q0 + ql;

  // bias slice: near halves only touch rel in [-121,121]; load [-186,189] (376 floats)
  for (int i = tid; i < 376; i += 256) Lb[i] = bt[(size_t)h * 2048 + 837 + i];  // 837 = 1023-186

  const unsigned short* Qp = Qb + (size_t)bh * SLEN * 64;
  const unsigned short* Kp = Kb + (size_t)bh * SLEN * 64;
  const unsigned short* Vp = Vt + (size_t)bh * 64 * SLEN;

  // Q as B-operand: col=lane&31=q, d contiguous 8 at hi*8 within each 16-chunk
  bf16x8 bq[4];
#pragma unroll
  for (int c = 0; c < 4; ++c)
    bq[c] = *(const bf16x8*)(Qp + (size_t)q * 64 + c * 16 + hi * 8);

  const f32x16 z16 = {0.f,0.f,0.f,0.f,0.f,0.f,0.f,0.f,0.f,0.f,0.f,0.f,0.f,0.f,0.f,0.f};
  f32x16 o0 = z16, o1 = z16;
  float m = -INFINITY, l = 0.f;

  // stage tile: 8KB K + 8KB V; wave w covers bytes [w*2048, w*2048+2048) of each.
  // linear LDS dest; source pre-inverse-swizzled so swizzled reads see [row][chunk^(row&7)].
  auto stage = [&](int buf, int kbase) {
#pragma unroll
    for (int j = 0; j < 2; ++j) {
      int lb = w * 2048 + j * 1024 + lane * 16;  // byte offset in tile
      int row = lb >> 7;
      int lc = ((lb >> 4) & 7) ^ (row & 7);
      gload_lds16(Kp + (size_t)(kbase + row) * 64 + lc * 8, &Ks[buf][w * 1024 + j * 512]);
      gload_lds16(Vp + (size_t)row * SLEN + kbase + lc * 8, &Vs[buf][w * 1024 + j * 512]);
    }
  };

  stage(0, 0);
  __syncthreads();  // covers Lb + stage(0); compiler drains vmcnt before s_barrier
  const float cpos = Lb[186 + 91], cneg = Lb[186 - 91];

  int cur = 0;
#pragma unroll 1
  for (int kt = 0; kt < 16; ++kt) {
    const int kbase = kt * 64;
    if (kt != 15) stage(cur ^ 1, kbase + 64);

    const char* Kc = (const char*)Ks[cur];
    const char* Vc = (const char*)Vs[cur];

#pragma unroll
    for (int hh = 0; hh < 2; ++hh) {
      const int kb32 = kbase + hh * 32;

      // K frags (A layout) from LDS: row = hh*32+ql, logical chunk c*2+hi, swizzled
      bf16x8 ak[4];
#pragma unroll
      for (int c = 0; c < 4; ++c) {
        const int ph = ((c << 1) | hi) ^ (ql & 7);
        ak[c] = *(const bf16x8*)(Kc + (hh * 32 + ql) * 128 + ph * 16);
      }

      // V frags (B layout) from LDS: row = dh*32+ql (d), logical chunk hh*4 + sl*2 + hi
      bf16x8 bv00, bv01, bv10, bv11;
      {
        const int p0 = ((hh << 2) | hi) ^ (ql & 7);        // sl=0 -> keys kb32+hi*8..
        const int p1 = ((hh << 2) | 2 | hi) ^ (ql & 7);    // sl=1 -> keys kb32+16+hi*8..
        bv00 = *(const bf16x8*)(Vc + ql * 128 + p0 * 16);
        bv01 = *(const bf16x8*)(Vc + (32 + ql) * 128 + p0 * 16);
        bv10 = *(const bf16x8*)(Vc + ql * 128 + p1 * 16);
        bv11 = *(const bf16x8*)(Vc + (32 + ql) * 128 + p1 * 16);
      }

      // QK^T: S[k][q]
      f32x16 s = z16;
      __builtin_amdgcn_s_setprio(1);
#pragma unroll
      for (int c = 0; c < 4; ++c) s = MFMA32(ak[c], bq[c], s);
      __builtin_amdgcn_s_setprio(0);

      // bias in log2 domain (per-32 classification, same as R3)
      const bool farp = (kb32 >= q0 + 122);   // min rel >= 91
      const bool farn = (kb32 + 122 <= q0);   // max rel <= -91
      if (farp || farn) {
        const float c = farp ? cpos : cneg;
#pragma unroll
        for (int r = 0; r < 16; ++r) s[r] = fmaf(s[r], LOG2E, c);
      } else {
        const int base = kb32 - q + 186 + hi * 4;
#pragma unroll
        for (int r = 0; r < 16; ++r)
          s[r] = fmaf(s[r], LOG2E, Lb[base + (r & 3) + 8 * (r >> 2)]);
      }

      // tile max for my q (in-register + one cross-half exchange)
      float vm = s[0];
#pragma unroll
      for (int r = 1; r < 16; ++r) vm = fmaxf(vm, s[r]);
      vm = fmaxf(vm, __shfl_xor(vm, 32));

      // defer-max rescale (THR=8 in log2 domain; algebraically exact)
      if (__any(vm > m + 8.0f)) {
        const float mn = fmaxf(m, vm);
        const float sc = fast_exp2(m - mn);   // exp2(-inf)=0 handles first tile
        m = mn;
        l *= sc;
        sred[w][ql] = sc;
        __builtin_amdgcn_wave_barrier();
#pragma unroll
        for (int r = 0; r < 16; ++r) {
          const float sr = sred[w][(r & 3) + 8 * (r >> 2) + hi * 4];
          o0[r] *= sr; o1[r] *= sr;
        }
        __builtin_amdgcn_wave_barrier();
      }

      // P = exp2(s - m), row sum
      float p[16];
      float ls = 0.f;
#pragma unroll
      for (int r = 0; r < 16; ++r) { p[r] = fast_exp2(s[r] - m); ls += p[r]; }
      l += ls + __shfl_xor(ls, 32);

      // pack P into PV A-operand frags (keys contiguous per lane via cross-half exchange)
      unsigned int wv[8], xv[8];
#pragma unroll
      for (int i = 0; i < 8; ++i) wv[i] = cvt_pk_bf16(p[2 * i], p[2 * i + 1]);
#pragma unroll
      for (int i = 0; i < 8; ++i) xv[i] = __shfl_xor(wv[i], 32);
      union { unsigned int u[4]; bf16x8 v; } pa0, pa1;
      pa0.u[0] = hi ? xv[2] : wv[0];
      pa0.u[1] = hi ? xv[3] : wv[1];
      pa0.u[2] = hi ? wv[2] : xv[0];
      pa0.u[3] = hi ? wv[3] : xv[1];
      pa1.u[0] = hi ? xv[6] : wv[4];
      pa1.u[1] = hi ? xv[7] : wv[5];
      pa1.u[2] = hi ? wv[6] : xv[4];
      pa1.u[3] = hi ? wv[7] : xv[5];

      // PV: O[q][d] += P[q][k] V[k][d]  (same accumulation order as R3)
      __builtin_amdgcn_s_setprio(1);
      o0 = MFMA32(pa0.v, bv00, o0);
      o0 = MFMA32(pa1.v, bv10, o0);
      o1 = MFMA32(pa0.v, bv01, o1);
      o1 = MFMA32(pa1.v, bv11, o1);
      __builtin_amdgcn_s_setprio(0);
    }

    __syncthreads();  // stage(cur^1) complete (vmcnt drained) + all reads of buf done
    cur ^= 1;
  }

  // finalize
  const float inv = 1.0f / l;
  sred[w][ql] = inv;
  __builtin_amdgcn_wave_barrier();
#pragma unroll
  for (int r = 0; r < 16; ++r) {
    const float ir = sred[w][(r & 3) + 8 * (r >> 2) + hi * 4];
    const int qq = q0 + (r & 3) + 8 * (r >> 2) + hi * 4;
    const size_t base = ((size_t)(b * 1024 + qq)) * 1024 + h * 64 + ql;
    ctx[base] = f2bf(o0[r] * ir);
    ctx[base + 32] = f2bf(o1[r] * ir);
  }
}

// ---------------- output projection: out = ctx @ wo (f32 out) ----------------
__global__ __launch_bounds__(256) void k_gemm_out(
    const unsigned short* __restrict__ Cb, const unsigned short* __restrict__ Wot,
    float* __restrict__ out) {
  __shared__ alignas(16) unsigned short As[128 * 40];
  __shared__ alignas(16) unsigned short Bs[128 * 40];
  int tm = (blockIdx.x >> 3) * 128, tn = (blockIdx.x & 7) * 128;
  f32x4 acc[4][4];
  gemm_tile_core(Cb, Wot, DMODEL, tm, tn, As, Bs, acc);

  const int lane = threadIdx.x & 63, w = threadIdx.x >> 6;
  const int wr = w >> 1, wc = w & 1, g = lane >> 4, t = lane & 15;
#pragma unroll
  for (int mi = 0; mi < 4; ++mi)
#pragma unroll
    for (int ni = 0; ni < 4; ++ni)
#pragma unroll
      for (int r = 0; r < 4; ++r) {
        int m = tm + wr * 64 + mi * 16 + g * 4 + r;
        int n = tn + wc * 64 + ni * 16 + t;
        out[(size_t)m * DMODEL + n] = acc[mi][ni][r];
      }
}

extern "C" void kernel_launch(void* const* d_in, const int* in_sizes, int n_in,
                              void* d_out, int out_size, void* d_ws, size_t ws_size,
                              hipStream_t stream) {
  const float* hs = (const float*)d_in[0];
  const float* wq = (const float*)d_in[1];
  const float* wk = (const float*)d_in[2];
  const float* wv = (const float*)d_in[3];
  const float* wo = (const float*)d_in[4];
  const float* rb = (const float*)d_in[5];

  char* ws = (char*)d_ws;
  unsigned short* Xb  = (unsigned short*)(ws + 0);          // 16 MB
  unsigned short* Wqt = (unsigned short*)(ws + 16777216);   // 2 MB
  unsigned short* Wkt = (unsigned short*)(ws + 18874368);
  unsigned short* Wvt = (unsigned short*)(ws + 20971520);
  unsigned short* Wot = (unsigned short*)(ws + 23068672);
  unsigned short* Qb  = (unsigned short*)(ws + 25165824);   // 16 MB
  unsigned short* Kb  = (unsigned short*)(ws + 41943040);   // 16 MB
  unsigned short* Vt  = (unsigned short*)(ws + 58720256);   // 16 MB
  unsigned short* Cb  = (unsigned short*)(ws + 75497472);   // 16 MB
  float* bt           = (float*)(ws + 92274688);            // 128 KB

  k_convert_x<<<4096, 256, 0, stream>>>(hs, Xb, NROWS * DMODEL);
  k_transpose_w<<<dim3(1024, 1, 4), 256, 0, stream>>>(wq, wk, wv, wo, Wqt, Wkt, Wvt, Wot);
  k_bias_table<<<128, 256, 0, stream>>>(rb, bt);
  k_gemm_qkv<<<dim3(512, 1, 3), 256, 0, stream>>>(Xb, Wqt, Wkt, Wvt, Qb, Kb, Vt);
  k_attn<<<1024, 256, 0, stream>>>(Qb, Kb, Vt, bt, Cb);
  k_gemm_out<<<512, 256, 0, stream>>>(Cb, Wot, (float*)d_out);
}

// Round 7
// 204.780 us; speedup vs baseline: 1.5240x; 1.0352x over previous
//
#include <hip/hip_runtime.h>
#include <stdint.h>

typedef __attribute__((ext_vector_type(8))) short bf16x8;
typedef __attribute__((ext_vector_type(4))) float f32x4;
typedef __attribute__((ext_vector_type(16))) float f32x16;
typedef __attribute__((ext_vector_type(8))) unsigned short ushort8;
typedef __attribute__((ext_vector_type(4))) unsigned short ushort4v;

#define MFMA16(a, b, c) __builtin_amdgcn_mfma_f32_16x16x32_bf16((a), (b), (c), 0, 0, 0)
#define MFMA32(a, b, c) __builtin_amdgcn_mfma_f32_32x32x16_bf16((a), (b), (c), 0, 0, 0)

// B=8, S=1024, D=1024, H=16, DK=64
#define SLEN 1024
#define NHEAD 16
#define HDIM 64
#define DMODEL 1024
#define NROWS 8192  // B*S
#define LOG2E 1.44269504088896340736f

__device__ __forceinline__ unsigned short f2bf(float f) {
  unsigned int u = __float_as_uint(f);
  u += 0x7FFFu + ((u >> 16) & 1u);   // RNE
  return (unsigned short)(u >> 16);
}

__device__ __forceinline__ float fast_exp2(float x) {
#if __has_builtin(__builtin_amdgcn_exp2f)
  return __builtin_amdgcn_exp2f(x);
#else
  float r; asm("v_exp_f32 %0, %1" : "=v"(r) : "v"(x)); return r;
#endif
}

__device__ __forceinline__ unsigned int cvt_pk_bf16(float lo, float hi) {
  unsigned int r;
  asm("v_cvt_pk_bf16_f32 %0, %1, %2" : "=v"(r) : "v"(lo), "v"(hi));
  return r;
}

// async global->LDS, 16B per lane; LDS dest = wave-uniform base + lane*16 (HW).
__device__ __forceinline__ void gload_lds16(const void* g, void* l) {
  __builtin_amdgcn_global_load_lds(
      (const __attribute__((address_space(1))) void*)g,
      (__attribute__((address_space(3))) void*)l, 16, 0, 0);
}

// ---------------- convert hidden_states f32 -> bf16 ----------------
__global__ __launch_bounds__(256) void k_convert_x(const float* __restrict__ x,
                                                   unsigned short* __restrict__ xb, int n) {
  int i = blockIdx.x * 256 + threadIdx.x;
  int idx = i * 8;
  if (idx >= n) return;
  float4 a = *(const float4*)(x + idx);
  float4 b = *(const float4*)(x + idx + 4);
  ushort8 o;
  o[0] = f2bf(a.x); o[1] = f2bf(a.y); o[2] = f2bf(a.z); o[3] = f2bf(a.w);
  o[4] = f2bf(b.x); o[5] = f2bf(b.y); o[6] = f2bf(b.z); o[7] = f2bf(b.w);
  *(ushort8*)(xb + idx) = o;
}

// ---------------- transpose + convert weights: W[K][N] f32 -> Wt[N][K] bf16 ----------------
__global__ __launch_bounds__(256) void k_transpose_w(
    const float* __restrict__ w0, const float* __restrict__ w1,
    const float* __restrict__ w2, const float* __restrict__ w3,
    unsigned short* __restrict__ o0, unsigned short* __restrict__ o1,
    unsigned short* __restrict__ o2, unsigned short* __restrict__ o3) {
  int z = blockIdx.z;
  const float* w = (z == 0) ? w0 : (z == 1) ? w1 : (z == 2) ? w2 : w3;
  unsigned short* o = (z == 0) ? o0 : (z == 1) ? o1 : (z == 2) ? o2 : o3;
  __shared__ unsigned short tile[32][33];
  int bx = blockIdx.x & 31, by = blockIdx.x >> 5;
  int tid = threadIdx.x;
#pragma unroll
  for (int p = 0; p < 4; ++p) {
    int idx = tid + p * 256;
    int r = idx >> 5, c = idx & 31;
    tile[r][c] = f2bf(w[(size_t)(by * 32 + r) * DMODEL + bx * 32 + c]);
  }
  __syncthreads();
#pragma unroll
  for (int p = 0; p < 4; ++p) {
    int idx = tid + p * 256;
    int r = idx >> 5, c = idx & 31;
    o[(size_t)(bx * 32 + r) * DMODEL + by * 32 + c] = tile[c][r];
  }
}

// ---------------- relative-position bias table: bt[h][rel+1023] * log2e, rel=k-q ----------------
__global__ __launch_bounds__(256) void k_bias_table(const float* __restrict__ rel_bias,
                                                    float* __restrict__ bt) {
  int i = blockIdx.x * 256 + threadIdx.x;
  if (i >= NHEAD * 2047) return;
  int h = i / 2047, rdx = i % 2047;
  int rel = rdx - 1023;
  int rb = (rel > 0) ? 16 : 0;
  int rp = (rel < 0) ? -rel : rel;
  int bucket;
  if (rp < 8) {
    bucket = rb + rp;
  } else {
    // large = 8 + floor(2*log2(rp)) - 6, capped at 15. Integer-exact via clz+square.
    int large;
    if (rp >= 91) {
      large = 15;
    } else {
      int nb = 31 - __clz(rp);
      long long sq = (long long)rp * rp;
      int f2 = 2 * nb + ((sq >= (1LL << (2 * nb + 1))) ? 1 : 0);
      large = 8 + (f2 - 6);
      if (large > 15) large = 15;
    }
    bucket = rb + large;
  }
  bt[h * 2048 + rdx] = rel_bias[bucket * 16 + h] * LOG2E;  // log2e domain
}

// ---------------- m97-style GEMM core: C[128x128] = A[M][K] * Bt[N][K]^T ----------------
// 256 threads = 4 waves (2x2), per-wave 64x64, 16x16x32 MFMA, BK=32.
// Staging via global_load_lds width=16 into linear [128][32] LDS (single-buffered,
// 2 barriers per K-step). A and B are both K-contiguous bf16.
__device__ __forceinline__ void gemm_tile_lds(const unsigned short* __restrict__ A,
                                              const unsigned short* __restrict__ Bt,
                                              int K, int tm, int tn,
                                              unsigned short* As, unsigned short* Bs,
                                              f32x4 acc[4][4]) {
  const int tid = threadIdx.x;
  const int lane = tid & 63;
  const int w = tid >> 6;
  const int wr = w >> 1, wc = w & 1;
  const int g = lane >> 4, t = lane & 15;
  const int NKT = K >> 5;

  // staging: 8 chunks of 1KB (16 rows each); wave w owns chunks 2w, 2w+1.
  // lane l covers row c*16 + (l>>2), col-chunk (l&3)*8 elements.
  const int c0 = 2 * w, c1 = 2 * w + 1;
  const int r0 = c0 * 16 + (lane >> 2), r1 = c1 * 16 + (lane >> 2);
  const int kc = (lane & 3) * 8;
  const unsigned short* Ag0 = A + (size_t)(tm + r0) * K + kc;
  const unsigned short* Ag1 = A + (size_t)(tm + r1) * K + kc;
  const unsigned short* Bg0 = Bt + (size_t)(tn + r0) * K + kc;
  const unsigned short* Bg1 = Bt + (size_t)(tn + r1) * K + kc;
  unsigned short* Ad0 = As + c0 * 512;
  unsigned short* Ad1 = As + c1 * 512;
  unsigned short* Bd0 = Bs + c0 * 512;
  unsigned short* Bd1 = Bs + c1 * 512;

  f32x4 z = {0.f, 0.f, 0.f, 0.f};
#pragma unroll
  for (int mi = 0; mi < 4; ++mi)
#pragma unroll
    for (int ni = 0; ni < 4; ++ni) acc[mi][ni] = z;

#pragma unroll 1
  for (int kt = 0; kt < NKT; ++kt) {
    const int ko = kt * 32;
    gload_lds16(Ag0 + ko, Ad0);
    gload_lds16(Ag1 + ko, Ad1);
    gload_lds16(Bg0 + ko, Bd0);
    gload_lds16(Bg1 + ko, Bd1);
    __syncthreads();  // drains vmcnt -> staged tile visible

    bf16x8 af[4], bfr[4];
#pragma unroll
    for (int mi = 0; mi < 4; ++mi)
      af[mi] = *(const bf16x8*)&As[(wr * 64 + mi * 16 + t) * 32 + g * 8];
#pragma unroll
    for (int ni = 0; ni < 4; ++ni)
      bfr[ni] = *(const bf16x8*)&Bs[(wc * 64 + ni * 16 + t) * 32 + g * 8];
#pragma unroll
    for (int mi = 0; mi < 4; ++mi)
#pragma unroll
      for (int ni = 0; ni < 4; ++ni)
        acc[mi][ni] = MFMA16(af[mi], bfr[ni], acc[mi][ni]);
    __syncthreads();  // all reads done before next stage overwrites
  }
}

// ---------------- QKV projection ----------------
__global__ __launch_bounds__(256) void k_gemm_qkv(
    const unsigned short* __restrict__ Xb,
    const unsigned short* __restrict__ Wqt, const unsigned short* __restrict__ Wkt,
    const unsigned short* __restrict__ Wvt,
    unsigned short* __restrict__ Qb, unsigned short* __restrict__ Kb,
    unsigned short* __restrict__ Vt) {
  __shared__ alignas(16) unsigned short As[128 * 32];
  __shared__ alignas(16) unsigned short Bs[128 * 32];
  int z = blockIdx.z;
  const unsigned short* Bt = (z == 0) ? Wqt : (z == 1) ? Wkt : Wvt;
  // XCD-aware swizzle (512 blocks % 8 == 0 -> bijective): each XCD owns an
  // 8-Mtile x 8-Ntile panel (2MB X slice, L2-resident).
  const int wid = (blockIdx.x & 7) * 64 + (blockIdx.x >> 3);
  int tm = (wid >> 3) * 128, tn = (wid & 7) * 128;
  f32x4 acc[4][4];
  gemm_tile_lds(Xb, Bt, DMODEL, tm, tn, As, Bs, acc);

  const int lane = threadIdx.x & 63, w = threadIdx.x >> 6;
  const int wr = w >> 1, wc = w & 1, g = lane >> 4, t = lane & 15;
  if (z < 2) {
    unsigned short* O = (z == 0) ? Qb : Kb;
#pragma unroll
    for (int mi = 0; mi < 4; ++mi)
#pragma unroll
      for (int ni = 0; ni < 4; ++ni)
#pragma unroll
        for (int r = 0; r < 4; ++r) {
          int m = tm + wr * 64 + mi * 16 + g * 4 + r;
          int n = tn + wc * 64 + ni * 16 + t;
          int b = m >> 10, s = m & 1023, h = n >> 6, d = n & 63;
          O[((size_t)((b * 16 + h) * 1024 + s)) * 64 + d] = f2bf(acc[mi][ni][r]);
        }
  } else {
#pragma unroll
    for (int mi = 0; mi < 4; ++mi)
#pragma unroll
      for (int ni = 0; ni < 4; ++ni) {
        int m0 = tm + wr * 64 + mi * 16 + g * 4;
        int n = tn + wc * 64 + ni * 16 + t;
        int b = m0 >> 10, s0 = m0 & 1023, h = n >> 6, d = n & 63;
        ushort4v pk;
#pragma unroll
        for (int r = 0; r < 4; ++r) pk[r] = f2bf(acc[mi][ni][r]);
        *(ushort4v*)&Vt[((size_t)((b * 16 + h) * 64 + d) * 1024) + s0] = pk;
      }
  }
}

// ---------------- flash attention (unchanged from R6 — verified) ----------------
// grid 1024 (XCD-swizzled); block 256 = 4 waves; wave = 32 q-rows.
// KVBLK=64 LDS tiles (double-buffered, global_load_lds, XOR swizzle); compute processes
// each tile as two sequential 32-key halves, op-for-op identical to the R3 kernel.
__global__ __launch_bounds__(256) void k_attn(
    const unsigned short* __restrict__ Qb, const unsigned short* __restrict__ Kb,
    const unsigned short* __restrict__ Vt, const float* __restrict__ bt,
    unsigned short* __restrict__ ctx) {
  __shared__ alignas(16) unsigned short Ks[2][64 * 64];  // [key][d] swizzled, 8KB each
  __shared__ alignas(16) unsigned short Vs[2][64 * 64];  // [d][key] swizzled, 8KB each
  __shared__ alignas(16) float Lb[376];                  // bias, rel in [-186,189], log2e domain
  __shared__ float sred[4][32];

  const int wid = ((blockIdx.x & 7) << 7) | (blockIdx.x >> 3);  // XCD-local head grouping
  const int bh = wid >> 3, qb = wid & 7;
  const int h = bh & 15, b = bh >> 4;
  const int tid = threadIdx.x;
  const int lane = tid & 63, w = tid >> 6;
  const int ql = lane & 31, hi = lane >> 5;
  const int q0 = qb * 128 + w * 32;
  const int q = q0 + ql;

  // bias slice: near halves only touch rel in [-121,121]; load [-186,189] (376 floats)
  for (int i = tid; i < 376; i += 256) Lb[i] = bt[(size_t)h * 2048 + 837 + i];  // 837 = 1023-186

  const unsigned short* Qp = Qb + (size_t)bh * SLEN * 64;
  const unsigned short* Kp = Kb + (size_t)bh * SLEN * 64;
  const unsigned short* Vp = Vt + (size_t)bh * 64 * SLEN;

  // Q as B-operand: col=lane&31=q, d contiguous 8 at hi*8 within each 16-chunk
  bf16x8 bq[4];
#pragma unroll
  for (int c = 0; c < 4; ++c)
    bq[c] = *(const bf16x8*)(Qp + (size_t)q * 64 + c * 16 + hi * 8);

  const f32x16 z16 = {0.f,0.f,0.f,0.f,0.f,0.f,0.f,0.f,0.f,0.f,0.f,0.f,0.f,0.f,0.f,0.f};
  f32x16 o0 = z16, o1 = z16;
  float m = -INFINITY, l = 0.f;

  // stage tile: 8KB K + 8KB V; wave w covers bytes [w*2048, w*2048+2048) of each.
  // linear LDS dest; source pre-inverse-swizzled so swizzled reads see [row][chunk^(row&7)].
  auto stage = [&](int buf, int kbase) {
#pragma unroll
    for (int j = 0; j < 2; ++j) {
      int lb = w * 2048 + j * 1024 + lane * 16;  // byte offset in tile
      int row = lb >> 7;
      int lc = ((lb >> 4) & 7) ^ (row & 7);
      gload_lds16(Kp + (size_t)(kbase + row) * 64 + lc * 8, &Ks[buf][w * 1024 + j * 512]);
      gload_lds16(Vp + (size_t)row * SLEN + kbase + lc * 8, &Vs[buf][w * 1024 + j * 512]);
    }
  };

  stage(0, 0);
  __syncthreads();  // covers Lb + stage(0); compiler drains vmcnt before s_barrier
  const float cpos = Lb[186 + 91], cneg = Lb[186 - 91];

  int cur = 0;
#pragma unroll 1
  for (int kt = 0; kt < 16; ++kt) {
    const int kbase = kt * 64;
    if (kt != 15) stage(cur ^ 1, kbase + 64);

    const char* Kc = (const char*)Ks[cur];
    const char* Vc = (const char*)Vs[cur];

#pragma unroll
    for (int hh = 0; hh < 2; ++hh) {
      const int kb32 = kbase + hh * 32;

      // K frags (A layout) from LDS: row = hh*32+ql, logical chunk c*2+hi, swizzled
      bf16x8 ak[4];
#pragma unroll
      for (int c = 0; c < 4; ++c) {
        const int ph = ((c << 1) | hi) ^ (ql & 7);
        ak[c] = *(const bf16x8*)(Kc + (hh * 32 + ql) * 128 + ph * 16);
      }

      // V frags (B layout) from LDS: row = dh*32+ql (d), logical chunk hh*4 + sl*2 + hi
      bf16x8 bv00, bv01, bv10, bv11;
      {
        const int p0 = ((hh << 2) | hi) ^ (ql & 7);        // sl=0 -> keys kb32+hi*8..
        const int p1 = ((hh << 2) | 2 | hi) ^ (ql & 7);    // sl=1 -> keys kb32+16+hi*8..
        bv00 = *(const bf16x8*)(Vc + ql * 128 + p0 * 16);
        bv01 = *(const bf16x8*)(Vc + (32 + ql) * 128 + p0 * 16);
        bv10 = *(const bf16x8*)(Vc + ql * 128 + p1 * 16);
        bv11 = *(const bf16x8*)(Vc + (32 + ql) * 128 + p1 * 16);
      }

      // QK^T: S[k][q]
      f32x16 s = z16;
      __builtin_amdgcn_s_setprio(1);
#pragma unroll
      for (int c = 0; c < 4; ++c) s = MFMA32(ak[c], bq[c], s);
      __builtin_amdgcn_s_setprio(0);

      // bias in log2 domain (per-32 classification, same as R3)
      const bool farp = (kb32 >= q0 + 122);   // min rel >= 91
      const bool farn = (kb32 + 122 <= q0);   // max rel <= -91
      if (farp || farn) {
        const float c = farp ? cpos : cneg;
#pragma unroll
        for (int r = 0; r < 16; ++r) s[r] = fmaf(s[r], LOG2E, c);
      } else {
        const int base = kb32 - q + 186 + hi * 4;
#pragma unroll
        for (int r = 0; r < 16; ++r)
          s[r] = fmaf(s[r], LOG2E, Lb[base + (r & 3) + 8 * (r >> 2)]);
      }

      // tile max for my q (in-register + one cross-half exchange)
      float vm = s[0];
#pragma unroll
      for (int r = 1; r < 16; ++r) vm = fmaxf(vm, s[r]);
      vm = fmaxf(vm, __shfl_xor(vm, 32));

      // defer-max rescale (THR=8 in log2 domain; algebraically exact)
      if (__any(vm > m + 8.0f)) {
        const float mn = fmaxf(m, vm);
        const float sc = fast_exp2(m - mn);   // exp2(-inf)=0 handles first tile
        m = mn;
        l *= sc;
        sred[w][ql] = sc;
        __builtin_amdgcn_wave_barrier();
#pragma unroll
        for (int r = 0; r < 16; ++r) {
          const float sr = sred[w][(r & 3) + 8 * (r >> 2) + hi * 4];
          o0[r] *= sr; o1[r] *= sr;
        }
        __builtin_amdgcn_wave_barrier();
      }

      // P = exp2(s - m), row sum
      float p[16];
      float ls = 0.f;
#pragma unroll
      for (int r = 0; r < 16; ++r) { p[r] = fast_exp2(s[r] - m); ls += p[r]; }
      l += ls + __shfl_xor(ls, 32);

      // pack P into PV A-operand frags (keys contiguous per lane via cross-half exchange)
      unsigned int wv[8], xv[8];
#pragma unroll
      for (int i = 0; i < 8; ++i) wv[i] = cvt_pk_bf16(p[2 * i], p[2 * i + 1]);
#pragma unroll
      for (int i = 0; i < 8; ++i) xv[i] = __shfl_xor(wv[i], 32);
      union { unsigned int u[4]; bf16x8 v; } pa0, pa1;
      pa0.u[0] = hi ? xv[2] : wv[0];
      pa0.u[1] = hi ? xv[3] : wv[1];
      pa0.u[2] = hi ? wv[2] : xv[0];
      pa0.u[3] = hi ? wv[3] : xv[1];
      pa1.u[0] = hi ? xv[6] : wv[4];
      pa1.u[1] = hi ? xv[7] : wv[5];
      pa1.u[2] = hi ? wv[6] : xv[4];
      pa1.u[3] = hi ? wv[7] : xv[5];

      // PV: O[q][d] += P[q][k] V[k][d]  (same accumulation order as R3)
      __builtin_amdgcn_s_setprio(1);
      o0 = MFMA32(pa0.v, bv00, o0);
      o0 = MFMA32(pa1.v, bv10, o0);
      o1 = MFMA32(pa0.v, bv01, o1);
      o1 = MFMA32(pa1.v, bv11, o1);
      __builtin_amdgcn_s_setprio(0);
    }

    __syncthreads();  // stage(cur^1) complete (vmcnt drained) + all reads of buf done
    cur ^= 1;
  }

  // finalize
  const float inv = 1.0f / l;
  sred[w][ql] = inv;
  __builtin_amdgcn_wave_barrier();
#pragma unroll
  for (int r = 0; r < 16; ++r) {
    const float ir = sred[w][(r & 3) + 8 * (r >> 2) + hi * 4];
    const int qq = q0 + (r & 3) + 8 * (r >> 2) + hi * 4;
    const size_t base = ((size_t)(b * 1024 + qq)) * 1024 + h * 64 + ql;
    ctx[base] = f2bf(o0[r] * ir);
    ctx[base + 32] = f2bf(o1[r] * ir);
  }
}

// ---------------- output projection: out = ctx @ wo (f32 out) ----------------
__global__ __launch_bounds__(256) void k_gemm_out(
    const unsigned short* __restrict__ Cb, const unsigned short* __restrict__ Wot,
    float* __restrict__ out) {
  __shared__ alignas(16) unsigned short As[128 * 32];
  __shared__ alignas(16) unsigned short Bs[128 * 32];
  const int wid = (blockIdx.x & 7) * 64 + (blockIdx.x >> 3);  // XCD swizzle
  int tm = (wid >> 3) * 128, tn = (wid & 7) * 128;
  f32x4 acc[4][4];
  gemm_tile_lds(Cb, Wot, DMODEL, tm, tn, As, Bs, acc);

  const int lane = threadIdx.x & 63, w = threadIdx.x >> 6;
  const int wr = w >> 1, wc = w & 1, g = lane >> 4, t = lane & 15;
#pragma unroll
  for (int mi = 0; mi < 4; ++mi)
#pragma unroll
    for (int ni = 0; ni < 4; ++ni)
#pragma unroll
      for (int r = 0; r < 4; ++r) {
        int m = tm + wr * 64 + mi * 16 + g * 4 + r;
        int n = tn + wc * 64 + ni * 16 + t;
        out[(size_t)m * DMODEL + n] = acc[mi][ni][r];
      }
}

extern "C" void kernel_launch(void* const* d_in, const int* in_sizes, int n_in,
                              void* d_out, int out_size, void* d_ws, size_t ws_size,
                              hipStream_t stream) {
  const float* hs = (const float*)d_in[0];
  const float* wq = (const float*)d_in[1];
  const float* wk = (const float*)d_in[2];
  const float* wv = (const float*)d_in[3];
  const float* wo = (const float*)d_in[4];
  const float* rb = (const float*)d_in[5];

  char* ws = (char*)d_ws;
  unsigned short* Xb  = (unsigned short*)(ws + 0);          // 16 MB
  unsigned short* Wqt = (unsigned short*)(ws + 16777216);   // 2 MB
  unsigned short* Wkt = (unsigned short*)(ws + 18874368);
  unsigned short* Wvt = (unsigned short*)(ws + 20971520);
  unsigned short* Wot = (unsigned short*)(ws + 23068672);
  unsigned short* Qb  = (unsigned short*)(ws + 25165824);   // 16 MB
  unsigned short* Kb  = (unsigned short*)(ws + 41943040);   // 16 MB
  unsigned short* Vt  = (unsigned short*)(ws + 58720256);   // 16 MB
  unsigned short* Cb  = (unsigned short*)(ws + 75497472);   // 16 MB
  float* bt           = (float*)(ws + 92274688);            // 128 KB

  k_convert_x<<<4096, 256, 0, stream>>>(hs, Xb, NROWS * DMODEL);
  k_transpose_w<<<dim3(1024, 1, 4), 256, 0, stream>>>(wq, wk, wv, wo, Wqt, Wkt, Wvt, Wot);
  k_bias_table<<<128, 256, 0, stream>>>(rb, bt);
  k_gemm_qkv<<<dim3(512, 1, 3), 256, 0, stream>>>(Xb, Wqt, Wkt, Wvt, Qb, Kb, Vt);
  k_attn<<<1024, 256, 0, stream>>>(Qb, Kb, Vt, bt, Cb);
  k_gemm_out<<<512, 256, 0, stream>>>(Cb, Wot, (float*)d_out);
}

// Round 8
// 187.662 us; speedup vs baseline: 1.6630x; 1.0912x over previous
//
#include <hip/hip_runtime.h>
#include <stdint.h>

typedef __attribute__((ext_vector_type(8))) short bf16x8;
typedef __attribute__((ext_vector_type(4))) float f32x4;
typedef __attribute__((ext_vector_type(16))) float f32x16;
typedef __attribute__((ext_vector_type(8))) unsigned short ushort8;
typedef __attribute__((ext_vector_type(4))) unsigned short ushort4v;

#define MFMA16(a, b, c) __builtin_amdgcn_mfma_f32_16x16x32_bf16((a), (b), (c), 0, 0, 0)
#define MFMA32(a, b, c) __builtin_amdgcn_mfma_f32_32x32x16_bf16((a), (b), (c), 0, 0, 0)

// B=8, S=1024, D=1024, H=16, DK=64
#define SLEN 1024
#define NHEAD 16
#define HDIM 64
#define DMODEL 1024
#define NROWS 8192  // B*S
#define LOG2E 1.44269504088896340736f

__device__ __forceinline__ unsigned short f2bf(float f) {
  unsigned int u = __float_as_uint(f);
  u += 0x7FFFu + ((u >> 16) & 1u);   // RNE
  return (unsigned short)(u >> 16);
}

__device__ __forceinline__ float fast_exp2(float x) {
#if __has_builtin(__builtin_amdgcn_exp2f)
  return __builtin_amdgcn_exp2f(x);
#else
  float r; asm("v_exp_f32 %0, %1" : "=v"(r) : "v"(x)); return r;
#endif
}

__device__ __forceinline__ unsigned int cvt_pk_bf16(float lo, float hi) {
  unsigned int r;
  asm("v_cvt_pk_bf16_f32 %0, %1, %2" : "=v"(r) : "v"(lo), "v"(hi));
  return r;
}

// async global->LDS, 16B per lane; LDS dest = wave-uniform base + lane*16 (HW).
__device__ __forceinline__ void gload_lds16(const void* g, void* l) {
  __builtin_amdgcn_global_load_lds(
      (const __attribute__((address_space(1))) void*)g,
      (__attribute__((address_space(3))) void*)l, 16, 0, 0);
}

// ---------------- convert hidden_states f32 -> bf16 ----------------
__global__ __launch_bounds__(256) void k_convert_x(const float* __restrict__ x,
                                                   unsigned short* __restrict__ xb, int n) {
  int i = blockIdx.x * 256 + threadIdx.x;
  int idx = i * 8;
  if (idx >= n) return;
  float4 a = *(const float4*)(x + idx);
  float4 b = *(const float4*)(x + idx + 4);
  ushort8 o;
  o[0] = f2bf(a.x); o[1] = f2bf(a.y); o[2] = f2bf(a.z); o[3] = f2bf(a.w);
  o[4] = f2bf(b.x); o[5] = f2bf(b.y); o[6] = f2bf(b.z); o[7] = f2bf(b.w);
  *(ushort8*)(xb + idx) = o;
}

// ---------------- transpose + convert weights: W[K][N] f32 -> Wt[N][K] bf16 ----------------
__global__ __launch_bounds__(256) void k_transpose_w(
    const float* __restrict__ w0, const float* __restrict__ w1,
    const float* __restrict__ w2, const float* __restrict__ w3,
    unsigned short* __restrict__ o0, unsigned short* __restrict__ o1,
    unsigned short* __restrict__ o2, unsigned short* __restrict__ o3) {
  int z = blockIdx.z;
  const float* w = (z == 0) ? w0 : (z == 1) ? w1 : (z == 2) ? w2 : w3;
  unsigned short* o = (z == 0) ? o0 : (z == 1) ? o1 : (z == 2) ? o2 : o3;
  __shared__ unsigned short tile[32][33];
  int bx = blockIdx.x & 31, by = blockIdx.x >> 5;
  int tid = threadIdx.x;
#pragma unroll
  for (int p = 0; p < 4; ++p) {
    int idx = tid + p * 256;
    int r = idx >> 5, c = idx & 31;
    tile[r][c] = f2bf(w[(size_t)(by * 32 + r) * DMODEL + bx * 32 + c]);
  }
  __syncthreads();
#pragma unroll
  for (int p = 0; p < 4; ++p) {
    int idx = tid + p * 256;
    int r = idx >> 5, c = idx & 31;
    o[(size_t)(bx * 32 + r) * DMODEL + by * 32 + c] = tile[c][r];
  }
}

// ---------------- relative-position bias table: bt[h][rel+1023] * log2e, rel=k-q ----------------
__global__ __launch_bounds__(256) void k_bias_table(const float* __restrict__ rel_bias,
                                                    float* __restrict__ bt) {
  int i = blockIdx.x * 256 + threadIdx.x;
  if (i >= NHEAD * 2047) return;
  int h = i / 2047, rdx = i % 2047;
  int rel = rdx - 1023;
  int rb = (rel > 0) ? 16 : 0;
  int rp = (rel < 0) ? -rel : rel;
  int bucket;
  if (rp < 8) {
    bucket = rb + rp;
  } else {
    // large = 8 + floor(2*log2(rp)) - 6, capped at 15. Integer-exact via clz+square.
    int large;
    if (rp >= 91) {
      large = 15;
    } else {
      int nb = 31 - __clz(rp);
      long long sq = (long long)rp * rp;
      int f2 = 2 * nb + ((sq >= (1LL << (2 * nb + 1))) ? 1 : 0);
      large = 8 + (f2 - 6);
      if (large > 15) large = 15;
    }
    bucket = rb + large;
  }
  bt[h * 2048 + rdx] = rel_bias[bucket * 16 + h] * LOG2E;  // log2e domain
}

// ---------------- 2-phase GEMM core: C[128x128] = A[M][K] * Bt[N][K]^T ----------------
// 256 threads = 4 waves (2x2), per-wave 64x64, 16x16x32 MFMA, BK=32.
// Double-buffered LDS (As/Bs = [2][128*32]); per K-step: issue STAGE(next buf) BEFORE
// compute(cur), single barrier per step (vmcnt drains after ~compute-phase of latency).
__device__ __forceinline__ void gemm_tile_lds(const unsigned short* __restrict__ A,
                                              const unsigned short* __restrict__ Bt,
                                              int K, int tm, int tn,
                                              unsigned short* As, unsigned short* Bs,
                                              f32x4 acc[4][4]) {
  const int tid = threadIdx.x;
  const int lane = tid & 63;
  const int w = tid >> 6;
  const int wr = w >> 1, wc = w & 1;
  const int g = lane >> 4, t = lane & 15;
  const int NKT = K >> 5;

  // staging: 8 chunks of 1KB (16 rows each); wave w owns chunks 2w, 2w+1.
  const int c0 = 2 * w, c1 = 2 * w + 1;
  const int r0 = c0 * 16 + (lane >> 2), r1 = c1 * 16 + (lane >> 2);
  const int kc = (lane & 3) * 8;
  const unsigned short* Ag0 = A + (size_t)(tm + r0) * K + kc;
  const unsigned short* Ag1 = A + (size_t)(tm + r1) * K + kc;
  const unsigned short* Bg0 = Bt + (size_t)(tn + r0) * K + kc;
  const unsigned short* Bg1 = Bt + (size_t)(tn + r1) * K + kc;

  f32x4 z = {0.f, 0.f, 0.f, 0.f};
#pragma unroll
  for (int mi = 0; mi < 4; ++mi)
#pragma unroll
    for (int ni = 0; ni < 4; ++ni) acc[mi][ni] = z;

  // prologue: stage buf0
  gload_lds16(Ag0, As + c0 * 512);
  gload_lds16(Ag1, As + c1 * 512);
  gload_lds16(Bg0, Bs + c0 * 512);
  gload_lds16(Bg1, Bs + c1 * 512);
  __syncthreads();

#pragma unroll 1
  for (int kt = 0; kt < NKT; ++kt) {
    const int cur = (kt & 1) * 4096;   // shorts: buf offset
    if (kt + 1 < NKT) {
      const int nxt = cur ^ 4096;
      const int ko = (kt + 1) * 32;
      gload_lds16(Ag0 + ko, As + nxt + c0 * 512);
      gload_lds16(Ag1 + ko, As + nxt + c1 * 512);
      gload_lds16(Bg0 + ko, Bs + nxt + c0 * 512);
      gload_lds16(Bg1 + ko, Bs + nxt + c1 * 512);
    }
    bf16x8 af[4], bfr[4];
#pragma unroll
    for (int mi = 0; mi < 4; ++mi)
      af[mi] = *(const bf16x8*)&As[cur + (wr * 64 + mi * 16 + t) * 32 + g * 8];
#pragma unroll
    for (int ni = 0; ni < 4; ++ni)
      bfr[ni] = *(const bf16x8*)&Bs[cur + (wc * 64 + ni * 16 + t) * 32 + g * 8];
#pragma unroll
    for (int mi = 0; mi < 4; ++mi)
#pragma unroll
      for (int ni = 0; ni < 4; ++ni)
        acc[mi][ni] = MFMA16(af[mi], bfr[ni], acc[mi][ni]);
    __syncthreads();  // drains vmcnt (next stage done, issued ~compute ago) + lgkm; syncs buf reuse
  }
}

// ---------------- QKV projection ----------------
__global__ __launch_bounds__(256) void k_gemm_qkv(
    const unsigned short* __restrict__ Xb,
    const unsigned short* __restrict__ Wqt, const unsigned short* __restrict__ Wkt,
    const unsigned short* __restrict__ Wvt,
    unsigned short* __restrict__ Qb, unsigned short* __restrict__ Kb,
    unsigned short* __restrict__ Vt) {
  __shared__ alignas(16) unsigned short As[2 * 128 * 32];
  __shared__ alignas(16) unsigned short Bs[2 * 128 * 32];
  int z = blockIdx.z;
  const unsigned short* Bt = (z == 0) ? Wqt : (z == 1) ? Wkt : Wvt;
  // XCD-aware swizzle (512 % 8 == 0 -> bijective): each XCD owns an 8x8 tile panel.
  const int wid = (blockIdx.x & 7) * 64 + (blockIdx.x >> 3);
  int tm = (wid >> 3) * 128, tn = (wid & 7) * 128;
  f32x4 acc[4][4];
  gemm_tile_lds(Xb, Bt, DMODEL, tm, tn, As, Bs, acc);

  const int lane = threadIdx.x & 63, w = threadIdx.x >> 6;
  const int wr = w >> 1, wc = w & 1, g = lane >> 4, t = lane & 15;
  if (z < 2) {
    unsigned short* O = (z == 0) ? Qb : Kb;
#pragma unroll
    for (int mi = 0; mi < 4; ++mi)
#pragma unroll
      for (int ni = 0; ni < 4; ++ni)
#pragma unroll
        for (int r = 0; r < 4; ++r) {
          int m = tm + wr * 64 + mi * 16 + g * 4 + r;
          int n = tn + wc * 64 + ni * 16 + t;
          int b = m >> 10, s = m & 1023, h = n >> 6, d = n & 63;
          O[((size_t)((b * 16 + h) * 1024 + s)) * 64 + d] = f2bf(acc[mi][ni][r]);
        }
  } else {
#pragma unroll
    for (int mi = 0; mi < 4; ++mi)
#pragma unroll
      for (int ni = 0; ni < 4; ++ni) {
        int m0 = tm + wr * 64 + mi * 16 + g * 4;
        int n = tn + wc * 64 + ni * 16 + t;
        int b = m0 >> 10, s0 = m0 & 1023, h = n >> 6, d = n & 63;
        ushort4v pk;
#pragma unroll
        for (int r = 0; r < 4; ++r) pk[r] = f2bf(acc[mi][ni][r]);
        *(ushort4v*)&Vt[((size_t)((b * 16 + h) * 64 + d) * 1024) + s0] = pk;
      }
  }
}

// ---------------- flash attention ----------------
// grid 512 (XCD-swizzled: each XCD owns 16 heads); block 512 = 8 waves; wave = 32 q-rows
// (256 q-rows/block). KVBLK=64 double-buffered LDS tiles staged by all 8 waves; per-wave
// compute op-for-op identical to R6 (bit-identical softmax).
__global__ __launch_bounds__(512) void k_attn(
    const unsigned short* __restrict__ Qb, const unsigned short* __restrict__ Kb,
    const unsigned short* __restrict__ Vt, const float* __restrict__ bt,
    unsigned short* __restrict__ ctx) {
  __shared__ alignas(16) unsigned short Ks[2][64 * 64];  // [key][d] swizzled, 8KB each
  __shared__ alignas(16) unsigned short Vs[2][64 * 64];  // [d][key] swizzled, 8KB each
  __shared__ alignas(16) float Lb[376];                  // bias, rel in [-186,189], log2e domain
  __shared__ float sred[8][32];

  const int wid = ((blockIdx.x & 7) << 6) | (blockIdx.x >> 3);  // XCD-local head grouping
  const int bh = wid >> 2, qb = wid & 3;
  const int h = bh & 15, b = bh >> 4;
  const int tid = threadIdx.x;
  const int lane = tid & 63, w = tid >> 6;
  const int ql = lane & 31, hi = lane >> 5;
  const int q0 = qb * 256 + w * 32;
  const int q = q0 + ql;

  // bias slice: near halves only touch rel in [-121,121]; load [-186,189] (376 floats)
  for (int i = tid; i < 376; i += 512) Lb[i] = bt[(size_t)h * 2048 + 837 + i];  // 837 = 1023-186

  const unsigned short* Qp = Qb + (size_t)bh * SLEN * 64;
  const unsigned short* Kp = Kb + (size_t)bh * SLEN * 64;
  const unsigned short* Vp = Vt + (size_t)bh * 64 * SLEN;

  // Q as B-operand: col=lane&31=q, d contiguous 8 at hi*8 within each 16-chunk
  bf16x8 bq[4];
#pragma unroll
  for (int c = 0; c < 4; ++c)
    bq[c] = *(const bf16x8*)(Qp + (size_t)q * 64 + c * 16 + hi * 8);

  const f32x16 z16 = {0.f,0.f,0.f,0.f,0.f,0.f,0.f,0.f,0.f,0.f,0.f,0.f,0.f,0.f,0.f,0.f};
  f32x16 o0 = z16, o1 = z16;
  float m = -INFINITY, l = 0.f;

  // stage tile: 8KB K + 8KB V; wave w covers bytes [w*1024, w*1024+1024) of each.
  // linear LDS dest; source pre-inverse-swizzled so swizzled reads see [row][chunk^(row&7)].
  auto stage = [&](int buf, int kbase) {
    int lb = w * 1024 + lane * 16;  // byte offset in 8KB tile
    int row = lb >> 7;              // w*8 + (lane>>3)
    int lc = ((lb >> 4) & 7) ^ (row & 7);
    gload_lds16(Kp + (size_t)(kbase + row) * 64 + lc * 8, &Ks[buf][w * 512]);
    gload_lds16(Vp + (size_t)row * SLEN + kbase + lc * 8, &Vs[buf][w * 512]);
  };

  stage(0, 0);
  __syncthreads();  // covers Lb + stage(0)
  const float cpos = Lb[186 + 91], cneg = Lb[186 - 91];

  int cur = 0;
#pragma unroll 1
  for (int kt = 0; kt < 16; ++kt) {
    const int kbase = kt * 64;
    if (kt != 15) stage(cur ^ 1, kbase + 64);

    const char* Kc = (const char*)Ks[cur];
    const char* Vc = (const char*)Vs[cur];

#pragma unroll
    for (int hh = 0; hh < 2; ++hh) {
      const int kb32 = kbase + hh * 32;

      // K frags (A layout) from LDS: row = hh*32+ql, logical chunk c*2+hi, swizzled
      bf16x8 ak[4];
#pragma unroll
      for (int c = 0; c < 4; ++c) {
        const int ph = ((c << 1) | hi) ^ (ql & 7);
        ak[c] = *(const bf16x8*)(Kc + (hh * 32 + ql) * 128 + ph * 16);
      }

      // V frags (B layout) from LDS: row = dh*32+ql (d), logical chunk hh*4 + sl*2 + hi
      bf16x8 bv00, bv01, bv10, bv11;
      {
        const int p0 = ((hh << 2) | hi) ^ (ql & 7);        // sl=0 -> keys kb32+hi*8..
        const int p1 = ((hh << 2) | 2 | hi) ^ (ql & 7);    // sl=1 -> keys kb32+16+hi*8..
        bv00 = *(const bf16x8*)(Vc + ql * 128 + p0 * 16);
        bv01 = *(const bf16x8*)(Vc + (32 + ql) * 128 + p0 * 16);
        bv10 = *(const bf16x8*)(Vc + ql * 128 + p1 * 16);
        bv11 = *(const bf16x8*)(Vc + (32 + ql) * 128 + p1 * 16);
      }

      // QK^T: S[k][q]
      f32x16 s = z16;
      __builtin_amdgcn_s_setprio(1);
#pragma unroll
      for (int c = 0; c < 4; ++c) s = MFMA32(ak[c], bq[c], s);
      __builtin_amdgcn_s_setprio(0);

      // bias in log2 domain (per-32 classification, same as R6)
      const bool farp = (kb32 >= q0 + 122);   // min rel >= 91
      const bool farn = (kb32 + 122 <= q0);   // max rel <= -91
      if (farp || farn) {
        const float c = farp ? cpos : cneg;
#pragma unroll
        for (int r = 0; r < 16; ++r) s[r] = fmaf(s[r], LOG2E, c);
      } else {
        const int base = kb32 - q + 186 + hi * 4;
#pragma unroll
        for (int r = 0; r < 16; ++r)
          s[r] = fmaf(s[r], LOG2E, Lb[base + (r & 3) + 8 * (r >> 2)]);
      }

      // tile max for my q (in-register + one cross-half exchange)
      float vm = s[0];
#pragma unroll
      for (int r = 1; r < 16; ++r) vm = fmaxf(vm, s[r]);
      vm = fmaxf(vm, __shfl_xor(vm, 32));

      // defer-max rescale (THR=8 in log2 domain; algebraically exact)
      if (__any(vm > m + 8.0f)) {
        const float mn = fmaxf(m, vm);
        const float sc = fast_exp2(m - mn);   // exp2(-inf)=0 handles first tile
        m = mn;
        l *= sc;
        sred[w][ql] = sc;
        __builtin_amdgcn_wave_barrier();
#pragma unroll
        for (int r = 0; r < 16; ++r) {
          const float sr = sred[w][(r & 3) + 8 * (r >> 2) + hi * 4];
          o0[r] *= sr; o1[r] *= sr;
        }
        __builtin_amdgcn_wave_barrier();
      }

      // P = exp2(s - m), row sum
      float p[16];
      float ls = 0.f;
#pragma unroll
      for (int r = 0; r < 16; ++r) { p[r] = fast_exp2(s[r] - m); ls += p[r]; }
      l += ls + __shfl_xor(ls, 32);

      // pack P into PV A-operand frags (keys contiguous per lane via cross-half exchange)
      unsigned int wv[8], xv[8];
#pragma unroll
      for (int i = 0; i < 8; ++i) wv[i] = cvt_pk_bf16(p[2 * i], p[2 * i + 1]);
#pragma unroll
      for (int i = 0; i < 8; ++i) xv[i] = __shfl_xor(wv[i], 32);
      union { unsigned int u[4]; bf16x8 v; } pa0, pa1;
      pa0.u[0] = hi ? xv[2] : wv[0];
      pa0.u[1] = hi ? xv[3] : wv[1];
      pa0.u[2] = hi ? wv[2] : xv[0];
      pa0.u[3] = hi ? wv[3] : xv[1];
      pa1.u[0] = hi ? xv[6] : wv[4];
      pa1.u[1] = hi ? xv[7] : wv[5];
      pa1.u[2] = hi ? wv[6] : xv[4];
      pa1.u[3] = hi ? wv[7] : xv[5];

      // PV: O[q][d] += P[q][k] V[k][d]  (same accumulation order as R6)
      __builtin_amdgcn_s_setprio(1);
      o0 = MFMA32(pa0.v, bv00, o0);
      o0 = MFMA32(pa1.v, bv10, o0);
      o1 = MFMA32(pa0.v, bv01, o1);
      o1 = MFMA32(pa1.v, bv11, o1);
      __builtin_amdgcn_s_setprio(0);
    }

    __syncthreads();  // stage(cur^1) complete (vmcnt drained) + all reads of buf done
    cur ^= 1;
  }

  // finalize
  const float inv = 1.0f / l;
  sred[w][ql] = inv;
  __builtin_amdgcn_wave_barrier();
#pragma unroll
  for (int r = 0; r < 16; ++r) {
    const float ir = sred[w][(r & 3) + 8 * (r >> 2) + hi * 4];
    const int qq = q0 + (r & 3) + 8 * (r >> 2) + hi * 4;
    const size_t base = ((size_t)(b * 1024 + qq)) * 1024 + h * 64 + ql;
    ctx[base] = f2bf(o0[r] * ir);
    ctx[base + 32] = f2bf(o1[r] * ir);
  }
}

// ---------------- output projection: out = ctx @ wo (f32 out) ----------------
__global__ __launch_bounds__(256) void k_gemm_out(
    const unsigned short* __restrict__ Cb, const unsigned short* __restrict__ Wot,
    float* __restrict__ out) {
  __shared__ alignas(16) unsigned short As[2 * 128 * 32];
  __shared__ alignas(16) unsigned short Bs[2 * 128 * 32];
  const int wid = (blockIdx.x & 7) * 64 + (blockIdx.x >> 3);  // XCD swizzle
  int tm = (wid >> 3) * 128, tn = (wid & 7) * 128;
  f32x4 acc[4][4];
  gemm_tile_lds(Cb, Wot, DMODEL, tm, tn, As, Bs, acc);

  const int lane = threadIdx.x & 63, w = threadIdx.x >> 6;
  const int wr = w >> 1, wc = w & 1, g = lane >> 4, t = lane & 15;
#pragma unroll
  for (int mi = 0; mi < 4; ++mi)
#pragma unroll
    for (int ni = 0; ni < 4; ++ni)
#pragma unroll
      for (int r = 0; r < 4; ++r) {
        int m = tm + wr * 64 + mi * 16 + g * 4 + r;
        int n = tn + wc * 64 + ni * 16 + t;
        out[(size_t)m * DMODEL + n] = acc[mi][ni][r];
      }
}

extern "C" void kernel_launch(void* const* d_in, const int* in_sizes, int n_in,
                              void* d_out, int out_size, void* d_ws, size_t ws_size,
                              hipStream_t stream) {
  const float* hs = (const float*)d_in[0];
  const float* wq = (const float*)d_in[1];
  const float* wk = (const float*)d_in[2];
  const float* wv = (const float*)d_in[3];
  const float* wo = (const float*)d_in[4];
  const float* rb = (const float*)d_in[5];

  char* ws = (char*)d_ws;
  unsigned short* Xb  = (unsigned short*)(ws + 0);          // 16 MB
  unsigned short* Wqt = (unsigned short*)(ws + 16777216);   // 2 MB
  unsigned short* Wkt = (unsigned short*)(ws + 18874368);
  unsigned short* Wvt = (unsigned short*)(ws + 20971520);
  unsigned short* Wot = (unsigned short*)(ws + 23068672);
  unsigned short* Qb  = (unsigned short*)(ws + 25165824);   // 16 MB
  unsigned short* Kb  = (unsigned short*)(ws + 41943040);   // 16 MB
  unsigned short* Vt  = (unsigned short*)(ws + 58720256);   // 16 MB
  unsigned short* Cb  = (unsigned short*)(ws + 75497472);   // 16 MB
  float* bt           = (float*)(ws + 92274688);            // 128 KB

  k_convert_x<<<4096, 256, 0, stream>>>(hs, Xb, NROWS * DMODEL);
  k_transpose_w<<<dim3(1024, 1, 4), 256, 0, stream>>>(wq, wk, wv, wo, Wqt, Wkt, Wvt, Wot);
  k_bias_table<<<128, 256, 0, stream>>>(rb, bt);
  k_gemm_qkv<<<dim3(512, 1, 3), 256, 0, stream>>>(Xb, Wqt, Wkt, Wvt, Qb, Kb, Vt);
  k_attn<<<512, 512, 0, stream>>>(Qb, Kb, Vt, bt, Cb);
  k_gemm_out<<<512, 256, 0, stream>>>(Cb, Wot, (float*)d_out);
}